// Round 1
// baseline (521.663 us; speedup 1.0000x reference)
//
#include <hip/hip_runtime.h>
#include <math.h>

#define NPTS   524288
#define GROUPS 4          // 16 pts/wave/group * 4 waves * 4 groups = 256 pts/block

typedef __attribute__((ext_vector_type(8))) short  short8;
typedef __attribute__((ext_vector_type(4))) float  f32x4;
typedef __attribute__((ext_vector_type(4))) int    int4v;

#define MFMA16(a, b, c) __builtin_amdgcn_mfma_f32_16x16x32_bf16((a), (b), (c), 0, 0, 0)
#define SB8(x) __builtin_bit_cast(short8, (x))

// wave-private LDS ordering: compile-time fence only (LDS executes in wave
// program order; block barrier not needed since LDS stripes are per-wave)
#define WFENCE() __builtin_amdgcn_wave_barrier()

// f32 -> bf16 bits, round-half-up
__device__ __forceinline__ unsigned bfbits(float x) {
    union { float f; unsigned u; } a; a.f = x;
    return (a.u + 0x8000u) >> 16;
}
#if __has_builtin(__builtin_amdgcn_cvt_pk_bf16_f32)
__device__ __forceinline__ int pk2(float lo, float hi) {
    return __builtin_bit_cast(int, __builtin_amdgcn_cvt_pk_bf16_f32(lo, hi));
}
#else
__device__ __forceinline__ int pk2(float lo, float hi) {
    union { float f; unsigned u; } a, b; a.f = lo; b.f = hi;
    return (int)(((a.u + 0x8000u) >> 16) | ((b.u + 0x8000u) & 0xFFFF0000u));
}
#endif

__device__ __forceinline__ float frcp(float x) {
#if __has_builtin(__builtin_amdgcn_rcpf)
    return __builtin_amdgcn_rcpf(x);   // ~1 ulp; fine at bf16 tolerance
#else
    return 1.f / x;
#endif
}

// coalesced global -> LDS direct copy, 16B per lane; lds dest must be wave-uniform
__device__ __forceinline__ void gload_lds16(const void* gp, void* lp_) {
    __builtin_amdgcn_global_load_lds(
        (__attribute__((address_space(1))) const void*)gp,
        (__attribute__((address_space(3))) void*)lp_, 16, 0, 0);
}

__device__ __forceinline__ f32x4 relub(f32x4 v, float b) {
    f32x4 r;
    #pragma unroll
    for (int i = 0; i < 4; ++i) r[i] = fmaxf(v[i] + b, 0.f);
    return r;
}

// sum across the 16 lanes of a quad (xor 1,2,4,8), per component
__device__ __forceinline__ f32x4 bfly16(f32x4 v) {
    #pragma unroll
    for (int d = 1; d <= 8; d <<= 1) {
        #pragma unroll
        for (int i = 0; i < 4; ++i) v[i] += __shfl_xor(v[i], d, 64);
    }
    return v;
}

// per-component softmax over 4 vectors (in place -> weights)
__device__ __forceinline__ void softmax4(f32x4& a, f32x4& b, f32x4& c, f32x4& d) {
    #pragma unroll
    for (int i = 0; i < 4; ++i) {
        float m  = fmaxf(fmaxf(a[i], b[i]), fmaxf(c[i], d[i]));
        float e0 = __expf(a[i] - m), e1 = __expf(b[i] - m);
        float e2 = __expf(c[i] - m), e3 = __expf(d[i] - m);
        float inv = frcp(e0 + e1 + e2 + e3);
        a[i] = e0 * inv; b[i] = e1 * inv; c[i] = e2 * inv; d[i] = e3 * inv;
    }
}

// dynamic component extract without scratch (cndmask tree)
__device__ __forceinline__ float sel4(f32x4 v, int r) {
    float a = (r & 1) ? v[1] : v[0];
    float b = (r & 1) ? v[3] : v[2];
    return (r & 2) ? b : a;
}

// ---------------- weight pre-pack kernel: 25 fragments x 64 lanes ----------------
// ws fragment index: bg(nt,ks)=nt*2+ks (0..3), bfc=4, blr(nt)=5+nt, bc(nt,ks)=9+nt*4+ks
// glob K is REORDERED to dword-aligned 20/20/20 sections:
//   k' 0..18 = v(ch), 19 = 0, 20..38 = var(ch), 39 = 0, 40..58 = mean(ch), 59..63 = 0
__global__ __launch_bounds__(64) void pack_weights(
    const float* __restrict__ glob_w, const float* __restrict__ fc_w,
    const float* __restrict__ lr0_w,  const float* __restrict__ col1_w,
    int4v* __restrict__ ws)
{
    const int f = blockIdx.x;
    const int l = threadIdx.x;
    const int q = l >> 4, lp = l & 15;
    short8 r;
    #pragma unroll
    for (int j = 0; j < 8; ++j) {
        int k = q * 8 + j;
        float v = 0.f;
        if (f < 4) {
            int kk = (f & 1) * 32 + k;
            if (kk < 60) {
                int sec = kk / 20, idx = kk - sec * 20;
                if (idx < 19) v = glob_w[((f >> 1) * 16 + lp) * 57 + sec * 19 + idx];
            }
        } else if (f == 4) {
            v = fc_w[lp * 32 + k];
        } else if (f < 9) {
            if (k < 24) v = lr0_w[((f - 5) * 16 + lp) * 24 + k];
        } else {
            int kk = ((f - 9) & 3) * 32 + k;
            if (kk < 111) v = col1_w[(((f - 9) >> 2) * 16 + lp) * 111 + kk];
        }
        r[j] = (short)bfbits(v);
    }
    ws[f * 64 + l] = __builtin_bit_cast(int4v, r);
}

// per-wave LDS region offsets (bytes).
// STG (f32 raw staging, 5888B used) is live stage1..3 only and is OVERLAID by
// FEATA (stages 4-5), XA (12-13), FCA (7-8), VIFA (post-3..13) — all written
// strictly after the staging reads complete (WFENCE separates).
#define STG   0        // 16 rows(pt) x 4 s x 92B = 5888
#define FEATA 0        // 4s x 4cc x 16row x 16B = 4096
#define XA    0        // 8c x 16row x 16B = 2048
#define FCA   2048     // 4c x 16row x 16B = 1024
#define VIFA  4096     // 4c x 16row x 16B = 1024 (vox / fc out / zeros, rewritten per iter)
#define RS    6144     // 3c x 64row x 16B = 3072 (raw img rows, bf16)
#define RGB   9216     // 64row x 16B = 1024     (rgb fp32)
#define WLDS  10240    // x4 waves = 40960 B/block -> exactly 4 blocks/CU

// evaluate one view-head channel + cross-sample mean/var via two INDEPENDENT
// 2-step shuffle chains: var = (Sum v^2 - (Sum v)^2/4)/3  (ddof=1)
#define CHEVAL(c, xv, vv, vrv, mv) do {                                    \
    xv = *(const float*)(st + 4 * (c));                                    \
    float vf_ = fmaf(d0, view_w[4 * (c) + 0], view_b[(c)]);                \
    vf_ = fmaf(d1, view_w[4 * (c) + 1], vf_);                              \
    vf_ = fmaf(d2, view_w[4 * (c) + 2], vf_);                              \
    vf_ = fmaf(d3, view_w[4 * (c) + 3], vf_);                              \
    vv = xv + fmaxf(vf_, 0.f);                                             \
    float p2_ = vv * vv;                                                   \
    float s1_ = vv + __shfl_xor(vv, 16, 64);  s1_ += __shfl_xor(s1_, 32, 64); \
    float s2_ = p2_ + __shfl_xor(p2_, 16, 64); s2_ += __shfl_xor(s2_, 32, 64); \
    mv  = s1_ * 0.25f;                                                     \
    vrv = fmaf(-s1_, mv, s2_) * (1.f / 3.f);                               \
} while (0)

__global__ __launch_bounds__(256, 4) void nerf_mfma(
    const float* __restrict__ vox, const float* __restrict__ img,
    const float* __restrict__ view_w, const float* __restrict__ view_b,
    const float* __restrict__ glob_b,
    const float* __restrict__ aggw_w, const float* __restrict__ aggw_b,
    const float* __restrict__ fc_b,
    const float* __restrict__ lr0_b,
    const float* __restrict__ sgm_w,  const float* __restrict__ sgm_b,
    const float* __restrict__ col1_b,
    const float* __restrict__ col2_w, const float* __restrict__ col2_b,
    const int4v* __restrict__ wsv,
    float* __restrict__ out)
{
    __shared__ int4v smem[(4 * WLDS) / 16];
    const int tid  = threadIdx.x;
    const int wv   = tid >> 6;
    const int lane = tid & 63;
    const int lp   = lane & 15;   // A-row point / C-column
    const int q    = lane >> 4;   // quad (= sample index in row-stages)
    char* S = (char*)smem + wv * WLDS;

    // ---- per-lane (column-indexed) biases/row-vectors ----
    const float gb0 = glob_b[lp], gb1 = glob_b[16 + lp];
    const float aw0 = aggw_w[lp], aw1 = aggw_w[16 + lp];
    const float fcb = fc_b[lp];
    float lb[4], sw[4], c1b[4], c2w[4];
    #pragma unroll
    for (int nt = 0; nt < 4; ++nt) {
        lb[nt]  = lr0_b[nt * 16 + lp];
        sw[nt]  = sgm_w[nt * 16 + lp];
        c1b[nt] = col1_b[nt * 16 + lp];
        c2w[nt] = col2_w[nt * 16 + lp];
    }
    const float ab0 = aggw_b[0], sb0 = sgm_b[0], c2b0 = col2_b[0];

    #pragma unroll 1
    for (int g = 0; g < GROUPS; ++g) {
        const int n0 = blockIdx.x * (64 * GROUPS) + g * 64 + wv * 16;

        // drain prior-iter LDS reads before async LDS-direct loads can land in STG
        asm volatile("s_waitcnt lgkmcnt(0)" ::: "memory");

        // ---------- stage 1: coalesced staging: 16 pts x 92B = 5888B -> LDS ----------
        {
            const char* gsrc = (const char*)img + (size_t)n0 * 368 + lane * 16;
            #pragma unroll
            for (int r = 0; r < 5; ++r)
                gload_lds16(gsrc + r * 1024, S + STG + r * 1024);
            if (lane < 48)   // last 768B of the 5888B region
                gload_lds16(gsrc + 5 * 1024, S + STG + 5 * 1024);
        }
        // vox load (q==0 lanes): coalesced 32B/pt, packed to bf16, held in regs
        int4v c8 = {0, 0, 0, 0};
        if (q == 0) {
            const float* vp = vox + (size_t)(n0 + lp) * 8;
            f32x4 v0 = *(const f32x4*)vp;
            f32x4 v1 = *(const f32x4*)(vp + 4);
            c8 = (int4v){ pk2(v0[0], v0[1]), pk2(v0[2], v0[3]),
                          pk2(v1[0], v1[1]), pk2(v1[2], v1[3]) };
        }
        asm volatile("s_waitcnt vmcnt(0)" ::: "memory");
        __builtin_amdgcn_sched_barrier(0);

        // ---------- stage 2+3: view head, mean/var, pack feat (K-reordered) ----------
        const char* st = (const char*)S + STG + (lp * 4 + q) * 92;
        const float d0 = *(const float*)(st + 76);
        const float d1 = *(const float*)(st + 80);
        const float d2 = *(const float*)(st + 84);
        const float d3 = *(const float*)(st + 88);

        unsigned pkf[32];
        pkf[30] = 0u; pkf[31] = 0u;
        unsigned rsbuf[4];
        float x16v = 0.f, x17v = 0.f, x18v = 0.f;

        #pragma unroll
        for (int cp = 0; cp < 10; ++cp) {
            const int a = 2 * cp;
            float xa, va, vra, ma;
            CHEVAL(a, xa, va, vra, ma);
            float xb = 0.f, vb = 0.f, vrb = 0.f, mb = 0.f;
            if (cp < 9) CHEVAL(a + 1, xb, vb, vrb, mb);
            pkf[cp]      = (unsigned)pk2(va,  vb);    // k' = 2cp,2cp+1   (v)
            pkf[10 + cp] = (unsigned)pk2(vra, vrb);   // k' = 20+2cp,...  (var)
            pkf[20 + cp] = (unsigned)pk2(ma,  mb);    // k' = 40+2cp,...  (mean)
            rsbuf[cp & 3] = (cp == 9) ? (unsigned)pk2(xa, d0) : (unsigned)pk2(xa, xb);
            if (cp == 3) {
                int4v w = {(int)rsbuf[0], (int)rsbuf[1], (int)rsbuf[2], (int)rsbuf[3]};
                *(int4v*)(S + RS + (q * 16 + lp) * 16) = w;
            }
            if (cp == 7) {
                int4v w = {(int)rsbuf[0], (int)rsbuf[1], (int)rsbuf[2], (int)rsbuf[3]};
                *(int4v*)(S + RS + 1024 + (q * 16 + lp) * 16) = w;
            }
            if (cp == 8) { x16v = xa; x17v = xb; }
            if (cp == 9) {
                x18v = xa;
                int4v w = {(int)rsbuf[0], (int)rsbuf[1], pk2(d1, d2), pk2(d3, 0.f)};
                *(int4v*)(S + RS + 2048 + (q * 16 + lp) * 16) = w;
            }
        }
        {
            f32x4 rgbv = { x16v, x17v, x18v, 0.f };
            *(f32x4*)(S + RGB + (q * 16 + lp) * 16) = rgbv;
        }
        WFENCE();   // all STG reads done; overlays (FEATA/VIFA) may now be written
        if (q == 0) *(int4v*)(S + VIFA + lp * 16) = c8;               // vif chunk 0 (vox)
        if (q == 3) {                                                  // vif chunk 3 (zeros)
            int4v zz = {0, 0, 0, 0};
            *(int4v*)(S + VIFA + (3 * 16 + lp) * 16) = zz;
        }

        // ---------- stage 4+5: glob GEMM, two K-passes through 4KB FEATA ----------
        f32x4 ag[4][2] = {};
        #pragma unroll
        for (int pass = 0; pass < 2; ++pass) {
            #pragma unroll
            for (int cc = 0; cc < 4; ++cc) {
                const int base = (pass * 4 + cc) * 4;
                int4v wv4 = { (int)pkf[base], (int)pkf[base + 1],
                              (int)pkf[base + 2], (int)pkf[base + 3] };
                *(int4v*)(S + FEATA + ((q * 4 + cc) * 16 + lp) * 16) = wv4;
            }
            WFENCE();
            int4v bg0 = wsv[(0 + pass) * 64 + lane];   // glob nt=0, ks=pass
            int4v bg1 = wsv[(2 + pass) * 64 + lane];   // glob nt=1, ks=pass
            #pragma unroll
            for (int s = 0; s < 4; ++s) {
                int4v av = *(int4v*)(S + FEATA + ((s * 4 + q) * 16 + lp) * 16);
                ag[s][0] = MFMA16(SB8(av), SB8(bg0), ag[s][0]);
                ag[s][1] = MFMA16(SB8(av), SB8(bg1), ag[s][1]);
            }
            WFENCE();
        }

        // ---------- stage 6: relu+agg softmax -> im_feat (C-layout lanes) ----------
        f32x4 gg[4][2], wsm[4];
        #pragma unroll
        for (int s = 0; s < 4; ++s) {
            gg[s][0] = relub(ag[s][0], gb0);
            gg[s][1] = relub(ag[s][1], gb1);
            f32x4 zp = gg[s][0] * aw0 + gg[s][1] * aw1;
            zp = bfly16(zp);
            wsm[s] = relub(zp, ab0);
        }
        softmax4(wsm[0], wsm[1], wsm[2], wsm[3]);
        f32x4 im0 = {}, im1 = {};
        #pragma unroll
        for (int s = 0; s < 4; ++s) { im0 += gg[s][0] * wsm[s]; im1 += gg[s][1] * wsm[s]; }

        // ---------- stage 7: scatter im_feat to fc A-fragments (bf16) ----------
        {
            short* fca = (short*)(S + FCA);
            #pragma unroll
            for (int r = 0; r < 4; ++r) {
                fca[((lp >> 3)) * 128     + (q * 4 + r) * 8 + (lp & 7)] = (short)bfbits(im0[r]);
                fca[(2 + (lp >> 3)) * 128 + (q * 4 + r) * 8 + (lp & 7)] = (short)bfbits(im1[r]);
            }
        }
        WFENCE();

        // ---------- stage 8: fc GEMM (rows=pts, cols=16, K=32) ----------
        f32x4 fco;
        {
            int4v av = *(int4v*)(S + FCA + (q * 16 + lp) * 16);
            int4v bfc = wsv[4 * 64 + lane];
            f32x4 acc = {};
            acc = MFMA16(SB8(av), SB8(bfc), acc);
            fco = relub(acc, fcb);
        }

        // ---------- stage 9: fc out -> vif chunks 1,2 ----------
        {
            short* vfa = (short*)(S + VIFA);
            #pragma unroll
            for (int r = 0; r < 4; ++r)
                vfa[(1 + (lp >> 3)) * 128 + (q * 4 + r) * 8 + (lp & 7)] = (short)bfbits(fco[r]);
        }
        WFENCE();

        // ---------- stage 10: lr0 GEMM (rows=pts, cols=64, K=32) ----------
        f32x4 x4[4];
        {
            int4v av = *(int4v*)(S + VIFA + (q * 16 + lp) * 16);
            #pragma unroll
            for (int nt = 0; nt < 4; ++nt) {
                int4v blr = wsv[(5 + nt) * 64 + lane];
                f32x4 acc = {};
                acc = MFMA16(SB8(av), SB8(blr), acc);
                x4[nt] = relub(acc, lb[nt]);
            }
        }

        // ---------- stage 11: sigma = softplus(sgm_w . x) ----------
        f32x4 sig;
        {
            f32x4 sp = x4[0] * sw[0] + x4[1] * sw[1] + x4[2] * sw[2] + x4[3] * sw[3];
            sp = bfly16(sp);
            #pragma unroll
            for (int i = 0; i < 4; ++i) {
                float z = sp[i] + sb0;
                float e = __expf(-fabsf(z));
                sig[i] = fmaxf(z, 0.f) + __logf(1.f + e);  // log1p(e), e in (0,1]
            }
        }

        // ---------- stage 12: x -> col1 A-fragments (chunks 0..7) ----------
        {
            short* xa = (short*)(S + XA);
            #pragma unroll
            for (int nt = 0; nt < 4; ++nt)
                #pragma unroll
                for (int r = 0; r < 4; ++r)
                    xa[(nt * 2 + (lp >> 3)) * 128 + (q * 4 + r) * 8 + (lp & 7)] =
                        (short)bfbits(x4[nt][r]);
        }
        WFENCE();

        // ---------- stage 13: col1 GEMM, nt-tiled with immediate col2 reduction ----------
        f32x4 zp[4] = {};
        {
            int4v ax0 = *(int4v*)(S + XA + (q * 16 + lp) * 16);
            int4v ax1 = *(int4v*)(S + XA + ((4 + q) * 16 + lp) * 16);
            int4v a2v[4], a3v[4];
            #pragma unroll
            for (int mt = 0; mt < 4; ++mt) {
                const char* a2p = (q < 3) ? (S + VIFA + (q * 16 + lp) * 16)
                                          : (S + RS + (mt * 16 + lp) * 16);
                const char* a3p = (q == 0) ? (S + RS + (64 + mt * 16 + lp) * 16)
                                : (q == 1) ? (S + RS + (128 + mt * 16 + lp) * 16)
                                           : (S + VIFA + (3 * 16 + lp) * 16);  // zeros
                a2v[mt] = *(const int4v*)a2p;
                a3v[mt] = *(const int4v*)a3p;
            }
            #pragma unroll
            for (int nt = 0; nt < 4; ++nt) {
                int4v b0 = wsv[(9 + nt * 4 + 0) * 64 + lane];
                int4v b1 = wsv[(9 + nt * 4 + 1) * 64 + lane];
                int4v b2 = wsv[(9 + nt * 4 + 2) * 64 + lane];
                int4v b3 = wsv[(9 + nt * 4 + 3) * 64 + lane];
                #pragma unroll
                for (int mt = 0; mt < 4; ++mt) {
                    f32x4 acc = {};
                    acc = MFMA16(SB8(ax0),      SB8(b0), acc);
                    acc = MFMA16(SB8(ax1),      SB8(b1), acc);
                    acc = MFMA16(SB8(a2v[mt]),  SB8(b2), acc);
                    acc = MFMA16(SB8(a3v[mt]),  SB8(b3), acc);
                    f32x4 h = relub(acc, c1b[nt]);
                    zp[mt] += h * c2w[nt];
                }
            }
        }

        // ---------- stage 14: softmax over s, color + store ----------
        f32x4 z2[4];
        #pragma unroll
        for (int s = 0; s < 4; ++s) z2[s] = relub(bfly16(zp[s]), c2b0);
        softmax4(z2[0], z2[1], z2[2], z2[3]);
        if (lp < 4) {
            float cr = 0.f, cg = 0.f, cb = 0.f;
            #pragma unroll
            for (int s = 0; s < 4; ++s) {
                f32x4 rgbv = *(f32x4*)(S + RGB + (s * 16 + q * 4 + lp) * 16);
                float ws = sel4(z2[s], lp);
                cr = fmaf(rgbv[0], ws, cr);
                cg = fmaf(rgbv[1], ws, cg);
                cb = fmaf(rgbv[2], ws, cb);
            }
            f32x4 o = { cr, cg, cb, sel4(sig, lp) };
            *(f32x4*)(out + (size_t)(n0 + q * 4 + lp) * 4) = o;
        }
        WFENCE();
    }
}

extern "C" void kernel_launch(void* const* d_in, const int* in_sizes, int n_in,
                              void* d_out, int out_size, void* d_ws, size_t ws_size,
                              hipStream_t stream) {
    (void)in_sizes; (void)n_in; (void)out_size; (void)ws_size;
    pack_weights<<<dim3(25), dim3(64), 0, stream>>>(
        (const float*)d_in[4],   // glob_w
        (const float*)d_in[8],   // fc_w
        (const float*)d_in[10],  // lr0_w
        (const float*)d_in[14],  // col1_w
        (int4v*)d_ws);
    nerf_mfma<<<dim3(NPTS / (64 * GROUPS)), dim3(256), 0, stream>>>(
        (const float*)d_in[0],  (const float*)d_in[1],
        (const float*)d_in[2],  (const float*)d_in[3],
        (const float*)d_in[5],
        (const float*)d_in[6],  (const float*)d_in[7],
        (const float*)d_in[9],
        (const float*)d_in[11],
        (const float*)d_in[12], (const float*)d_in[13],
        (const float*)d_in[15],
        (const float*)d_in[16], (const float*)d_in[17],
        (const int4v*)d_ws,
        (float*)d_out);
}

// Round 2
// 492.341 us; speedup vs baseline: 1.0596x; 1.0596x over previous
//
#include <hip/hip_runtime.h>
#include <math.h>

#define NPTS   524288
#define GROUPS 4          // 16 pts/wave/group * 4 waves * 4 groups = 256 pts/block

typedef __attribute__((ext_vector_type(8))) short  short8;
typedef __attribute__((ext_vector_type(4))) float  f32x4;
typedef __attribute__((ext_vector_type(4))) int    int4v;

#define MFMA16(a, b, c) __builtin_amdgcn_mfma_f32_16x16x32_bf16((a), (b), (c), 0, 0, 0)
#define SB8(x) __builtin_bit_cast(short8, (x))

// wave-private LDS ordering: compile-time fence only (LDS executes in wave
// program order; block barrier not needed since LDS stripes are per-wave)
#define WFENCE() __builtin_amdgcn_wave_barrier()

// f32 -> bf16 bits, round-half-up
__device__ __forceinline__ unsigned bfbits(float x) {
    union { float f; unsigned u; } a; a.f = x;
    return (a.u + 0x8000u) >> 16;
}
#if __has_builtin(__builtin_amdgcn_cvt_pk_bf16_f32)
__device__ __forceinline__ int pk2(float lo, float hi) {
    return __builtin_bit_cast(int, __builtin_amdgcn_cvt_pk_bf16_f32(lo, hi));
}
#else
__device__ __forceinline__ int pk2(float lo, float hi) {
    union { float f; unsigned u; } a, b; a.f = lo; b.f = hi;
    return (int)(((a.u + 0x8000u) >> 16) | ((b.u + 0x8000u) & 0xFFFF0000u));
}
#endif

__device__ __forceinline__ float frcp(float x) {
#if __has_builtin(__builtin_amdgcn_rcpf)
    return __builtin_amdgcn_rcpf(x);   // ~1 ulp; fine at bf16 tolerance
#else
    return 1.f / x;
#endif
}

// coalesced global -> LDS direct copy, 16B per lane; lds dest must be wave-uniform
__device__ __forceinline__ void gload_lds16(const void* gp, void* lp_) {
    __builtin_amdgcn_global_load_lds(
        (__attribute__((address_space(1))) const void*)gp,
        (__attribute__((address_space(3))) void*)lp_, 16, 0, 0);
}

__device__ __forceinline__ f32x4 relub(f32x4 v, float b) {
    f32x4 r;
    #pragma unroll
    for (int i = 0; i < 4; ++i) r[i] = fmaxf(v[i] + b, 0.f);
    return r;
}

// sum across the 16 lanes of a quad (xor 1,2,4,8), per component
__device__ __forceinline__ f32x4 bfly16(f32x4 v) {
    #pragma unroll
    for (int d = 1; d <= 8; d <<= 1) {
        #pragma unroll
        for (int i = 0; i < 4; ++i) v[i] += __shfl_xor(v[i], d, 64);
    }
    return v;
}

// per-component softmax over 4 vectors (in place -> weights)
__device__ __forceinline__ void softmax4(f32x4& a, f32x4& b, f32x4& c, f32x4& d) {
    #pragma unroll
    for (int i = 0; i < 4; ++i) {
        float m  = fmaxf(fmaxf(a[i], b[i]), fmaxf(c[i], d[i]));
        float e0 = __expf(a[i] - m), e1 = __expf(b[i] - m);
        float e2 = __expf(c[i] - m), e3 = __expf(d[i] - m);
        float inv = frcp(e0 + e1 + e2 + e3);
        a[i] = e0 * inv; b[i] = e1 * inv; c[i] = e2 * inv; d[i] = e3 * inv;
    }
}

// dynamic component extract without scratch (cndmask tree)
__device__ __forceinline__ float sel4(f32x4 v, int r) {
    float a = (r & 1) ? v[1] : v[0];
    float b = (r & 1) ? v[3] : v[2];
    return (r & 2) ? b : a;
}

// ---------------- weight pre-pack kernel: 25 fragments x 64 lanes ----------------
// ws fragment index: bg(nt,ks)=nt*2+ks (0..3), bfc=4, blr(nt)=5+nt, bc(nt,ks)=9+nt*4+ks
// glob K is REORDERED to dword-aligned 20/20/20 sections:
//   k' 0..18 = v(ch), 19 = 0, 20..38 = var(ch), 39 = 0, 40..58 = mean(ch), 59..63 = 0
__global__ __launch_bounds__(64) void pack_weights(
    const float* __restrict__ glob_w, const float* __restrict__ fc_w,
    const float* __restrict__ lr0_w,  const float* __restrict__ col1_w,
    int4v* __restrict__ ws)
{
    const int f = blockIdx.x;
    const int l = threadIdx.x;
    const int q = l >> 4, lp = l & 15;
    short8 r;
    #pragma unroll
    for (int j = 0; j < 8; ++j) {
        int k = q * 8 + j;
        float v = 0.f;
        if (f < 4) {
            int kk = (f & 1) * 32 + k;
            if (kk < 60) {
                int sec = kk / 20, idx = kk - sec * 20;
                if (idx < 19) v = glob_w[((f >> 1) * 16 + lp) * 57 + sec * 19 + idx];
            }
        } else if (f == 4) {
            v = fc_w[lp * 32 + k];
        } else if (f < 9) {
            if (k < 24) v = lr0_w[((f - 5) * 16 + lp) * 24 + k];
        } else {
            int kk = ((f - 9) & 3) * 32 + k;
            if (kk < 111) v = col1_w[(((f - 9) >> 2) * 16 + lp) * 111 + kk];
        }
        r[j] = (short)bfbits(v);
    }
    ws[f * 64 + l] = __builtin_bit_cast(int4v, r);
}

// per-wave LDS region offsets (bytes).
// STG (f32 raw staging, 5888B used) is live stage1..3 only and is OVERLAID by
// FEATA (stages 4-5), XA (12-13), FCA (7-8), VIFA (post-3..13) — all written
// strictly after the staging reads complete (WFENCE separates).
#define STG   0        // 16 rows(pt) x 4 s x 92B = 5888
#define FEATA 0        // 4s x 4cc x 16row x 16B = 4096
#define XA    0        // 8c x 16row x 16B = 2048
#define FCA   2048     // 4c x 16row x 16B = 1024
#define VIFA  4096     // 4c x 16row x 16B = 1024 (vox / fc out / zeros, rewritten per iter)
#define RS    6144     // 3c x 64row x 16B = 3072 (raw img rows, bf16)
#define RGB   9216     // 64row x 16B = 1024     (rgb fp32)
#define WLDS  10240    // x4 waves = 40960 B/block -> 3 blocks/CU (VGPR-capped at 3 waves/SIMD)

// evaluate one view-head channel + cross-sample mean/var via two INDEPENDENT
// 2-step shuffle chains: var = (Sum v^2 - (Sum v)^2/4)/3  (ddof=1)
#define CHEVAL(c, xv, vv, vrv, mv) do {                                    \
    xv = *(const float*)(st + 4 * (c));                                    \
    float vf_ = fmaf(d0, view_w[4 * (c) + 0], view_b[(c)]);                \
    vf_ = fmaf(d1, view_w[4 * (c) + 1], vf_);                              \
    vf_ = fmaf(d2, view_w[4 * (c) + 2], vf_);                              \
    vf_ = fmaf(d3, view_w[4 * (c) + 3], vf_);                              \
    vv = xv + fmaxf(vf_, 0.f);                                             \
    float p2_ = vv * vv;                                                   \
    float s1_ = vv + __shfl_xor(vv, 16, 64);  s1_ += __shfl_xor(s1_, 32, 64); \
    float s2_ = p2_ + __shfl_xor(p2_, 16, 64); s2_ += __shfl_xor(s2_, 32, 64); \
    mv  = s1_ * 0.25f;                                                     \
    vrv = fmaf(-s1_, mv, s2_) * (1.f / 3.f);                               \
} while (0)

__global__ __launch_bounds__(256, 3) void nerf_mfma(
    const float* __restrict__ vox, const float* __restrict__ img,
    const float* __restrict__ view_w, const float* __restrict__ view_b,
    const float* __restrict__ glob_b,
    const float* __restrict__ aggw_w, const float* __restrict__ aggw_b,
    const float* __restrict__ fc_b,
    const float* __restrict__ lr0_b,
    const float* __restrict__ sgm_w,  const float* __restrict__ sgm_b,
    const float* __restrict__ col1_b,
    const float* __restrict__ col2_w, const float* __restrict__ col2_b,
    const int4v* __restrict__ wsv,
    float* __restrict__ out)
{
    __shared__ int4v smem[(4 * WLDS) / 16];
    const int tid  = threadIdx.x;
    const int wv   = tid >> 6;
    const int lane = tid & 63;
    const int lp   = lane & 15;   // A-row point / C-column
    const int q    = lane >> 4;   // quad (= sample index in row-stages)
    char* S = (char*)smem + wv * WLDS;

    // ---- per-lane (column-indexed) biases/row-vectors ----
    const float gb0 = glob_b[lp], gb1 = glob_b[16 + lp];
    const float aw0 = aggw_w[lp], aw1 = aggw_w[16 + lp];
    const float fcb = fc_b[lp];
    float lb[4], sw[4], c1b[4], c2w[4];
    #pragma unroll
    for (int nt = 0; nt < 4; ++nt) {
        lb[nt]  = lr0_b[nt * 16 + lp];
        sw[nt]  = sgm_w[nt * 16 + lp];
        c1b[nt] = col1_b[nt * 16 + lp];
        c2w[nt] = col2_w[nt * 16 + lp];
    }
    const float ab0 = aggw_b[0], sb0 = sgm_b[0], c2b0 = col2_b[0];

    #pragma unroll 1
    for (int g = 0; g < GROUPS; ++g) {
        const int n0 = blockIdx.x * (64 * GROUPS) + g * 64 + wv * 16;

        // opaque zero: makes weight-load addresses loop-variant so LICM cannot
        // hoist+pin all 25 fragments (100 VGPRs) across the whole loop body
        int zoff = 0;
        asm volatile("" : "+v"(zoff));

        // drain prior-iter LDS reads before async LDS-direct loads can land in STG
        asm volatile("s_waitcnt lgkmcnt(0)" ::: "memory");

        // ---------- stage 1a: coalesced staging: 16 pts x 92B = 5888B -> LDS ----------
        {
            const char* gsrc = (const char*)img + (size_t)n0 * 368 + lane * 16;
            #pragma unroll
            for (int r = 0; r < 5; ++r)
                gload_lds16(gsrc + r * 1024, S + STG + r * 1024);
            if (lane < 48)   // last 768B of the 5888B region
                gload_lds16(gsrc + 5 * 1024, S + STG + 5 * 1024);
        }
        __builtin_amdgcn_sched_barrier(0);   // staging issues stay oldest in vmcnt order

        // ---------- stage 1b: vox + batch-1 weight fragments (fly under stage 2/3) ----
        // vox: all lanes load point lp (q-redundant, L1-served) -> no divergence
        const float* vp = vox + (size_t)(n0 + lp) * 8;
        f32x4 v0 = *(const f32x4*)vp;
        f32x4 v1 = *(const f32x4*)(vp + 4);
        int4v bg0_[2], bg1_[2], blr[4], bfc;
        #pragma unroll
        for (int ks = 0; ks < 2; ++ks) {
            bg0_[ks] = wsv[(0 + ks) * 64 + lane + zoff];
            bg1_[ks] = wsv[(2 + ks) * 64 + lane + zoff];
        }
        bfc = wsv[4 * 64 + lane + zoff];
        #pragma unroll
        for (int nt = 0; nt < 4; ++nt) blr[nt] = wsv[(5 + nt) * 64 + lane + zoff];

        __builtin_amdgcn_sched_barrier(0);
        // 6 staging + 2 vox + 9 weights outstanding -> wait for the 6 oldest
        // (staging) only; vox/weights keep flying under the VALU stage below.
        asm volatile("s_waitcnt vmcnt(11)" ::: "memory");
        __builtin_amdgcn_sched_barrier(0);

        // ---------- stage 2+3: view head, mean/var, pack feat (K-reordered) ----------
        const char* st = (const char*)S + STG + (lp * 4 + q) * 92;
        const float d0 = *(const float*)(st + 76);
        const float d1 = *(const float*)(st + 80);
        const float d2 = *(const float*)(st + 84);
        const float d3 = *(const float*)(st + 88);

        unsigned pkf[32];
        pkf[30] = 0u; pkf[31] = 0u;
        unsigned rsbuf[4];
        float x16v = 0.f, x17v = 0.f, x18v = 0.f;

        #pragma unroll
        for (int cp = 0; cp < 10; ++cp) {
            const int a = 2 * cp;
            float xa, va, vra, ma;
            CHEVAL(a, xa, va, vra, ma);
            float xb = 0.f, vb = 0.f, vrb = 0.f, mb = 0.f;
            if (cp < 9) CHEVAL(a + 1, xb, vb, vrb, mb);
            pkf[cp]      = (unsigned)pk2(va,  vb);    // k' = 2cp,2cp+1   (v)
            pkf[10 + cp] = (unsigned)pk2(vra, vrb);   // k' = 20+2cp,...  (var)
            pkf[20 + cp] = (unsigned)pk2(ma,  mb);    // k' = 40+2cp,...  (mean)
            rsbuf[cp & 3] = (cp == 9) ? (unsigned)pk2(xa, d0) : (unsigned)pk2(xa, xb);
            if (cp == 3) {
                int4v w = {(int)rsbuf[0], (int)rsbuf[1], (int)rsbuf[2], (int)rsbuf[3]};
                *(int4v*)(S + RS + (q * 16 + lp) * 16) = w;
            }
            if (cp == 7) {
                int4v w = {(int)rsbuf[0], (int)rsbuf[1], (int)rsbuf[2], (int)rsbuf[3]};
                *(int4v*)(S + RS + 1024 + (q * 16 + lp) * 16) = w;
            }
            if (cp == 8) { x16v = xa; x17v = xb; }
            if (cp == 9) {
                x18v = xa;
                int4v w = {(int)rsbuf[0], (int)rsbuf[1], pk2(d1, d2), pk2(d3, 0.f)};
                *(int4v*)(S + RS + 2048 + (q * 16 + lp) * 16) = w;
            }
        }
        {
            f32x4 rgbv = { x16v, x17v, x18v, 0.f };
            *(f32x4*)(S + RGB + (q * 16 + lp) * 16) = rgbv;
        }
        WFENCE();   // all STG reads done; overlays (FEATA/VIFA) may now be written
        if (q == 0) {                                                  // vif chunk 0 (vox)
            int4v c8 = { pk2(v0[0], v0[1]), pk2(v0[2], v0[3]),
                         pk2(v1[0], v1[1]), pk2(v1[2], v1[3]) };
            *(int4v*)(S + VIFA + lp * 16) = c8;
        }
        if (q == 3) {                                                  // vif chunk 3 (zeros)
            int4v zz = {0, 0, 0, 0};
            *(int4v*)(S + VIFA + (3 * 16 + lp) * 16) = zz;
        }

        // ---------- stage 4+5: glob GEMM, two K-passes through 4KB FEATA ----------
        f32x4 ag[4][2] = {};
        #pragma unroll
        for (int pass = 0; pass < 2; ++pass) {
            #pragma unroll
            for (int cc = 0; cc < 4; ++cc) {
                const int base = (pass * 4 + cc) * 4;
                int4v wv4 = { (int)pkf[base], (int)pkf[base + 1],
                              (int)pkf[base + 2], (int)pkf[base + 3] };
                *(int4v*)(S + FEATA + ((q * 4 + cc) * 16 + lp) * 16) = wv4;
            }
            WFENCE();
            #pragma unroll
            for (int s = 0; s < 4; ++s) {
                int4v av = *(int4v*)(S + FEATA + ((s * 4 + q) * 16 + lp) * 16);
                ag[s][0] = MFMA16(SB8(av), SB8(bg0_[pass]), ag[s][0]);
                ag[s][1] = MFMA16(SB8(av), SB8(bg1_[pass]), ag[s][1]);
            }
            WFENCE();
        }

        // ---------- stage 6: relu+agg softmax -> im_feat (C-layout lanes) ----------
        f32x4 gg[4][2], wsm[4];
        #pragma unroll
        for (int s = 0; s < 4; ++s) {
            gg[s][0] = relub(ag[s][0], gb0);
            gg[s][1] = relub(ag[s][1], gb1);
            f32x4 zp = gg[s][0] * aw0 + gg[s][1] * aw1;
            zp = bfly16(zp);
            wsm[s] = relub(zp, ab0);
        }
        softmax4(wsm[0], wsm[1], wsm[2], wsm[3]);
        f32x4 im0 = {}, im1 = {};
        #pragma unroll
        for (int s = 0; s < 4; ++s) { im0 += gg[s][0] * wsm[s]; im1 += gg[s][1] * wsm[s]; }

        // ---------- batch-2 weight fragments (col1): issue now (pkf dead), ----------
        // ---------- consumed at stage 13 -> L2 latency hides under stages 7-12 -------
        int4v bc[16];
        #pragma unroll
        for (int f = 0; f < 16; ++f) bc[f] = wsv[(9 + f) * 64 + lane + zoff];

        // ---------- stage 7: scatter im_feat to fc A-fragments (bf16) ----------
        {
            short* fca = (short*)(S + FCA);
            #pragma unroll
            for (int r = 0; r < 4; ++r) {
                fca[((lp >> 3)) * 128     + (q * 4 + r) * 8 + (lp & 7)] = (short)bfbits(im0[r]);
                fca[(2 + (lp >> 3)) * 128 + (q * 4 + r) * 8 + (lp & 7)] = (short)bfbits(im1[r]);
            }
        }
        WFENCE();

        // ---------- stage 8: fc GEMM (rows=pts, cols=16, K=32) ----------
        f32x4 fco;
        {
            int4v av = *(int4v*)(S + FCA + (q * 16 + lp) * 16);
            f32x4 acc = {};
            acc = MFMA16(SB8(av), SB8(bfc), acc);
            fco = relub(acc, fcb);
        }

        // ---------- stage 9: fc out -> vif chunks 1,2 ----------
        {
            short* vfa = (short*)(S + VIFA);
            #pragma unroll
            for (int r = 0; r < 4; ++r)
                vfa[(1 + (lp >> 3)) * 128 + (q * 4 + r) * 8 + (lp & 7)] = (short)bfbits(fco[r]);
        }
        WFENCE();

        // ---------- stage 10: lr0 GEMM (rows=pts, cols=64, K=32) ----------
        f32x4 x4[4];
        {
            int4v av = *(int4v*)(S + VIFA + (q * 16 + lp) * 16);
            #pragma unroll
            for (int nt = 0; nt < 4; ++nt) {
                f32x4 acc = {};
                acc = MFMA16(SB8(av), SB8(blr[nt]), acc);
                x4[nt] = relub(acc, lb[nt]);
            }
        }

        // ---------- stage 11: sigma = softplus(sgm_w . x) ----------
        f32x4 sig;
        {
            f32x4 sp = x4[0] * sw[0] + x4[1] * sw[1] + x4[2] * sw[2] + x4[3] * sw[3];
            sp = bfly16(sp);
            #pragma unroll
            for (int i = 0; i < 4; ++i) {
                float z = sp[i] + sb0;
                float e = __expf(-fabsf(z));
                sig[i] = fmaxf(z, 0.f) + __logf(1.f + e);  // log1p(e), e in (0,1]
            }
        }

        // ---------- stage 12: x -> col1 A-fragments (chunks 0..7) ----------
        {
            short* xa = (short*)(S + XA);
            #pragma unroll
            for (int nt = 0; nt < 4; ++nt)
                #pragma unroll
                for (int r = 0; r < 4; ++r)
                    xa[(nt * 2 + (lp >> 3)) * 128 + (q * 4 + r) * 8 + (lp & 7)] =
                        (short)bfbits(x4[nt][r]);
        }
        WFENCE();

        // ---------- stage 13: col1 GEMM, nt-tiled with immediate col2 reduction ----------
        f32x4 zp[4] = {};
        {
            int4v ax0 = *(int4v*)(S + XA + (q * 16 + lp) * 16);
            int4v ax1 = *(int4v*)(S + XA + ((4 + q) * 16 + lp) * 16);
            int4v a2v[4], a3v[4];
            #pragma unroll
            for (int mt = 0; mt < 4; ++mt) {
                const char* a2p = (q < 3) ? (S + VIFA + (q * 16 + lp) * 16)
                                          : (S + RS + (mt * 16 + lp) * 16);
                const char* a3p = (q == 0) ? (S + RS + (64 + mt * 16 + lp) * 16)
                                : (q == 1) ? (S + RS + (128 + mt * 16 + lp) * 16)
                                           : (S + VIFA + (3 * 16 + lp) * 16);  // zeros
                a2v[mt] = *(const int4v*)a2p;
                a3v[mt] = *(const int4v*)a3p;
            }
            #pragma unroll
            for (int nt = 0; nt < 4; ++nt) {
                #pragma unroll
                for (int mt = 0; mt < 4; ++mt) {
                    f32x4 acc = {};
                    acc = MFMA16(SB8(ax0),      SB8(bc[nt * 4 + 0]), acc);
                    acc = MFMA16(SB8(ax1),      SB8(bc[nt * 4 + 1]), acc);
                    acc = MFMA16(SB8(a2v[mt]),  SB8(bc[nt * 4 + 2]), acc);
                    acc = MFMA16(SB8(a3v[mt]),  SB8(bc[nt * 4 + 3]), acc);
                    f32x4 h = relub(acc, c1b[nt]);
                    zp[mt] += h * c2w[nt];
                }
            }
        }

        // ---------- stage 14: softmax over s, color + store ----------
        f32x4 z2[4];
        #pragma unroll
        for (int s = 0; s < 4; ++s) z2[s] = relub(bfly16(zp[s]), c2b0);
        softmax4(z2[0], z2[1], z2[2], z2[3]);
        if (lp < 4) {
            float cr = 0.f, cg = 0.f, cb = 0.f;
            #pragma unroll
            for (int s = 0; s < 4; ++s) {
                f32x4 rgbv = *(f32x4*)(S + RGB + (s * 16 + q * 4 + lp) * 16);
                float ws = sel4(z2[s], lp);
                cr = fmaf(rgbv[0], ws, cr);
                cg = fmaf(rgbv[1], ws, cg);
                cb = fmaf(rgbv[2], ws, cb);
            }
            f32x4 o = { cr, cg, cb, sel4(sig, lp) };
            *(f32x4*)(out + (size_t)(n0 + q * 4 + lp) * 4) = o;
        }
        WFENCE();
    }
}

extern "C" void kernel_launch(void* const* d_in, const int* in_sizes, int n_in,
                              void* d_out, int out_size, void* d_ws, size_t ws_size,
                              hipStream_t stream) {
    (void)in_sizes; (void)n_in; (void)out_size; (void)ws_size;
    pack_weights<<<dim3(25), dim3(64), 0, stream>>>(
        (const float*)d_in[4],   // glob_w
        (const float*)d_in[8],   // fc_w
        (const float*)d_in[10],  // lr0_w
        (const float*)d_in[14],  // col1_w
        (int4v*)d_ws);
    nerf_mfma<<<dim3(NPTS / (64 * GROUPS)), dim3(256), 0, stream>>>(
        (const float*)d_in[0],  (const float*)d_in[1],
        (const float*)d_in[2],  (const float*)d_in[3],
        (const float*)d_in[5],
        (const float*)d_in[6],  (const float*)d_in[7],
        (const float*)d_in[9],
        (const float*)d_in[11],
        (const float*)d_in[12], (const float*)d_in[13],
        (const float*)d_in[15],
        (const float*)d_in[16], (const float*)d_in[17],
        (const int4v*)d_ws,
        (float*)d_out);
}

// Round 3
// 438.305 us; speedup vs baseline: 1.1902x; 1.1233x over previous
//
#include <hip/hip_runtime.h>
#include <math.h>

#define NPTS   524288
#define GROUPS 4          // 16 pts/wave/group * 4 waves * 4 groups = 256 pts/block

typedef __attribute__((ext_vector_type(8))) short  short8;
typedef __attribute__((ext_vector_type(4))) float  f32x4;
typedef __attribute__((ext_vector_type(4))) int    int4v;

#define MFMA16(a, b, c) __builtin_amdgcn_mfma_f32_16x16x32_bf16((a), (b), (c), 0, 0, 0)
#define SB8(x) __builtin_bit_cast(short8, (x))

// wave-private LDS ordering: compile-time fence only (LDS executes in wave
// program order; block barrier not needed since LDS stripes are per-wave)
#define WFENCE() __builtin_amdgcn_wave_barrier()

// f32 -> bf16 bits, round-half-up
__device__ __forceinline__ unsigned bfbits(float x) {
    union { float f; unsigned u; } a; a.f = x;
    return (a.u + 0x8000u) >> 16;
}
#if __has_builtin(__builtin_amdgcn_cvt_pk_bf16_f32)
__device__ __forceinline__ int pk2(float lo, float hi) {
    return __builtin_bit_cast(int, __builtin_amdgcn_cvt_pk_bf16_f32(lo, hi));
}
#else
__device__ __forceinline__ int pk2(float lo, float hi) {
    union { float f; unsigned u; } a, b; a.f = lo; b.f = hi;
    return (int)(((a.u + 0x8000u) >> 16) | ((b.u + 0x8000u) & 0xFFFF0000u));
}
#endif

__device__ __forceinline__ float frcp(float x) {
#if __has_builtin(__builtin_amdgcn_rcpf)
    return __builtin_amdgcn_rcpf(x);   // ~1 ulp; fine at bf16 tolerance
#else
    return 1.f / x;
#endif
}

// coalesced global -> LDS direct copy, 16B per lane; lds dest must be wave-uniform
__device__ __forceinline__ void gload_lds16(const void* gp, void* lp_) {
    __builtin_amdgcn_global_load_lds(
        (__attribute__((address_space(1))) const void*)gp,
        (__attribute__((address_space(3))) void*)lp_, 16, 0, 0);
}

__device__ __forceinline__ f32x4 relub(f32x4 v, float b) {
    f32x4 r;
    #pragma unroll
    for (int i = 0; i < 4; ++i) r[i] = fmaxf(v[i] + b, 0.f);
    return r;
}

// sum across the 16 lanes of a quad (xor 1,2,4,8), per component
__device__ __forceinline__ f32x4 bfly16(f32x4 v) {
    #pragma unroll
    for (int d = 1; d <= 8; d <<= 1) {
        #pragma unroll
        for (int i = 0; i < 4; ++i) v[i] += __shfl_xor(v[i], d, 64);
    }
    return v;
}

// per-component softmax over 4 vectors (in place -> weights)
__device__ __forceinline__ void softmax4(f32x4& a, f32x4& b, f32x4& c, f32x4& d) {
    #pragma unroll
    for (int i = 0; i < 4; ++i) {
        float m  = fmaxf(fmaxf(a[i], b[i]), fmaxf(c[i], d[i]));
        float e0 = __expf(a[i] - m), e1 = __expf(b[i] - m);
        float e2 = __expf(c[i] - m), e3 = __expf(d[i] - m);
        float inv = frcp(e0 + e1 + e2 + e3);
        a[i] = e0 * inv; b[i] = e1 * inv; c[i] = e2 * inv; d[i] = e3 * inv;
    }
}

// dynamic component extract without scratch (cndmask tree)
__device__ __forceinline__ float sel4(f32x4 v, int r) {
    float a = (r & 1) ? v[1] : v[0];
    float b = (r & 1) ? v[3] : v[2];
    return (r & 2) ? b : a;
}

// ---------------- weight pre-pack kernel: 25 fragments x 64 lanes ----------------
// ws fragment index: bg(nt,ks)=nt*2+ks (0..3), bfc=4, blr(nt)=5+nt, bc(nt,ks)=9+nt*4+ks
// glob K is REORDERED to dword-aligned 20/20/20 sections:
//   k' 0..18 = v(ch), 19 = 0, 20..38 = var(ch), 39 = 0, 40..58 = mean(ch), 59..63 = 0
__global__ __launch_bounds__(64) void pack_weights(
    const float* __restrict__ glob_w, const float* __restrict__ fc_w,
    const float* __restrict__ lr0_w,  const float* __restrict__ col1_w,
    int4v* __restrict__ ws)
{
    const int f = blockIdx.x;
    const int l = threadIdx.x;
    const int q = l >> 4, lp = l & 15;
    short8 r;
    #pragma unroll
    for (int j = 0; j < 8; ++j) {
        int k = q * 8 + j;
        float v = 0.f;
        if (f < 4) {
            int kk = (f & 1) * 32 + k;
            if (kk < 60) {
                int sec = kk / 20, idx = kk - sec * 20;
                if (idx < 19) v = glob_w[((f >> 1) * 16 + lp) * 57 + sec * 19 + idx];
            }
        } else if (f == 4) {
            v = fc_w[lp * 32 + k];
        } else if (f < 9) {
            if (k < 24) v = lr0_w[((f - 5) * 16 + lp) * 24 + k];
        } else {
            int kk = ((f - 9) & 3) * 32 + k;
            if (kk < 111) v = col1_w[(((f - 9) >> 2) * 16 + lp) * 111 + kk];
        }
        r[j] = (short)bfbits(v);
    }
    ws[f * 64 + l] = __builtin_bit_cast(int4v, r);
}

// per-wave LDS region offsets (bytes).
// STG (f32 raw staging, 5888B used) is now DISJOINT from the overlay block so
// group g+1's staging can fly while stages 4-14 of group g use FEATA/XA/FCA/VIFA.
#define FEATA 0        // 4s x 4cc x 16row x 16B = 4096 (stages 4-5)
#define XA    0        // 8c x 16row x 16B = 2048       (stages 12-13)
#define FCA   2048     // 4c x 16row x 16B = 1024       (stages 7-8)
#define VIFA  4096     // 4c x 16row x 16B = 1024       (vox / fc out / zeros)
#define RS    6144     // 3c x 64row x 16B = 3072       (raw img rows, bf16)
#define RGB   9216     // 64row x 16B = 1024            (rgb fp32)
#define STG   10240    // 16 pts x 92B = 5888           (live stages 1-3 only)
#define WLDS  16384    // x4 waves = 65536 B/block -> 2 blocks/CU (VGPRs cap at 2 anyway)

// evaluate one view-head channel + cross-sample mean/var via two INDEPENDENT
// 2-step shuffle chains: var = (Sum v^2 - (Sum v)^2/4)/3  (ddof=1)
#define CHEVAL(c, xv, vv, vrv, mv) do {                                    \
    xv = *(const float*)(st + 4 * (c));                                    \
    float vf_ = fmaf(d0, view_w[4 * (c) + 0], view_b[(c)]);                \
    vf_ = fmaf(d1, view_w[4 * (c) + 1], vf_);                              \
    vf_ = fmaf(d2, view_w[4 * (c) + 2], vf_);                              \
    vf_ = fmaf(d3, view_w[4 * (c) + 3], vf_);                              \
    vv = xv + fmaxf(vf_, 0.f);                                             \
    float p2_ = vv * vv;                                                   \
    float s1_ = vv + __shfl_xor(vv, 16, 64);  s1_ += __shfl_xor(s1_, 32, 64); \
    float s2_ = p2_ + __shfl_xor(p2_, 16, 64); s2_ += __shfl_xor(s2_, 32, 64); \
    mv  = s1_ * 0.25f;                                                     \
    vrv = fmaf(-s1_, mv, s2_) * (1.f / 3.f);                               \
} while (0)

__global__ __launch_bounds__(256, 2) void nerf_mfma(
    const float* __restrict__ vox, const float* __restrict__ img,
    const float* __restrict__ view_w, const float* __restrict__ view_b,
    const float* __restrict__ glob_b,
    const float* __restrict__ aggw_w, const float* __restrict__ aggw_b,
    const float* __restrict__ fc_b,
    const float* __restrict__ lr0_b,
    const float* __restrict__ sgm_w,  const float* __restrict__ sgm_b,
    const float* __restrict__ col1_b,
    const float* __restrict__ col2_w, const float* __restrict__ col2_b,
    const int4v* __restrict__ wsv,
    float* __restrict__ out)
{
    __shared__ int4v smem[(4 * WLDS) / 16];
    const int tid  = threadIdx.x;
    const int wv   = tid >> 6;
    const int lane = tid & 63;
    const int lp   = lane & 15;   // A-row point / C-column
    const int q    = lane >> 4;   // quad (= sample index in row-stages)
    char* S = (char*)smem + wv * WLDS;

    // ---- per-lane (column-indexed) biases/row-vectors ----
    const float gb0 = glob_b[lp], gb1 = glob_b[16 + lp];
    const float aw0 = aggw_w[lp], aw1 = aggw_w[16 + lp];
    const float fcb = fc_b[lp];
    float lb[4], sw[4], c1b[4], c2w[4];
    #pragma unroll
    for (int nt = 0; nt < 4; ++nt) {
        lb[nt]  = lr0_b[nt * 16 + lp];
        sw[nt]  = sgm_w[nt * 16 + lp];
        c1b[nt] = col1_b[nt * 16 + lp];
        c2w[nt] = col2_w[nt * 16 + lp];
    }
    const float ab0 = aggw_b[0], sb0 = sgm_b[0], c2b0 = col2_b[0];

    // ---- hoisted weight fragments: 25 x 16B = 100 VGPRs, live whole kernel ----
    // (256-VGPR budget from __launch_bounds__(256,2): no spill, loaded ONCE)
    int4v bgf[2][2], bfcf, blrf[4], bcf[16];
    #pragma unroll
    for (int ks = 0; ks < 2; ++ks) {
        bgf[0][ks] = wsv[(0 + ks) * 64 + lane];
        bgf[1][ks] = wsv[(2 + ks) * 64 + lane];
    }
    bfcf = wsv[4 * 64 + lane];
    #pragma unroll
    for (int nt = 0; nt < 4; ++nt) blrf[nt] = wsv[(5 + nt) * 64 + lane];
    #pragma unroll
    for (int f = 0; f < 16; ++f) bcf[f] = wsv[(9 + f) * 64 + lane];

    const int nb0 = blockIdx.x * (64 * GROUPS) + wv * 16;

    auto issue_stage = [&](int nbase) {
        const char* gsrc = (const char*)img + (size_t)nbase * 368 + lane * 16;
        #pragma unroll
        for (int r = 0; r < 5; ++r)
            gload_lds16(gsrc + r * 1024, S + STG + r * 1024);
        if (lane < 48)   // last 768B of the 5888B region
            gload_lds16(gsrc + 5 * 1024, S + STG + 5 * 1024);
    };

    // prologue: stage group 0
    issue_stage(nb0);

    #pragma unroll 1
    for (int g = 0; g < GROUPS; ++g) {
        const int n0 = nb0 + g * 64;

        // staging for this group complete (prefetched under previous group's
        // compute; first iter also drains the weight loads once)
        asm volatile("s_waitcnt vmcnt(0)" ::: "memory");
        __builtin_amdgcn_sched_barrier(0);

        // vox loads fly under stage 2/3 (compiler-managed wait at c8 pack)
        const float* vp = vox + (size_t)(n0 + lp) * 8;
        f32x4 v0 = *(const f32x4*)vp;
        f32x4 v1 = *(const f32x4*)(vp + 4);

        // ---------- stage 2+3: view head, mean/var, pack feat (K-reordered) ----------
        const char* st = (const char*)S + STG + (lp * 4 + q) * 92;
        const float d0 = *(const float*)(st + 76);
        const float d1 = *(const float*)(st + 80);
        const float d2 = *(const float*)(st + 84);
        const float d3 = *(const float*)(st + 88);

        unsigned pkf[32];
        pkf[30] = 0u; pkf[31] = 0u;
        unsigned rsbuf[4];
        float x16v = 0.f, x17v = 0.f, x18v = 0.f;

        #pragma unroll
        for (int cp = 0; cp < 10; ++cp) {
            const int a = 2 * cp;
            float xa, va, vra, ma;
            CHEVAL(a, xa, va, vra, ma);
            float xb = 0.f, vb = 0.f, vrb = 0.f, mb = 0.f;
            if (cp < 9) CHEVAL(a + 1, xb, vb, vrb, mb);
            pkf[cp]      = (unsigned)pk2(va,  vb);    // k' = 2cp,2cp+1   (v)
            pkf[10 + cp] = (unsigned)pk2(vra, vrb);   // k' = 20+2cp,...  (var)
            pkf[20 + cp] = (unsigned)pk2(ma,  mb);    // k' = 40+2cp,...  (mean)
            rsbuf[cp & 3] = (cp == 9) ? (unsigned)pk2(xa, d0) : (unsigned)pk2(xa, xb);
            if (cp == 3) {
                int4v w = {(int)rsbuf[0], (int)rsbuf[1], (int)rsbuf[2], (int)rsbuf[3]};
                *(int4v*)(S + RS + (q * 16 + lp) * 16) = w;
            }
            if (cp == 7) {
                int4v w = {(int)rsbuf[0], (int)rsbuf[1], (int)rsbuf[2], (int)rsbuf[3]};
                *(int4v*)(S + RS + 1024 + (q * 16 + lp) * 16) = w;
            }
            if (cp == 8) { x16v = xa; x17v = xb; }
            if (cp == 9) {
                x18v = xa;
                int4v w = {(int)rsbuf[0], (int)rsbuf[1], pk2(d1, d2), pk2(d3, 0.f)};
                *(int4v*)(S + RS + 2048 + (q * 16 + lp) * 16) = w;
            }
        }
        {
            f32x4 rgbv = { x16v, x17v, x18v, 0.f };
            *(f32x4*)(S + RGB + (q * 16 + lp) * 16) = rgbv;
        }
        WFENCE();   // all STG reads consumed; VIFA may be written, STG is dead
        if (q == 0) {                                                  // vif chunk 0 (vox)
            int4v c8 = { pk2(v0[0], v0[1]), pk2(v0[2], v0[3]),
                         pk2(v1[0], v1[1]), pk2(v1[2], v1[3]) };
            *(int4v*)(S + VIFA + lp * 16) = c8;
        }
        if (q == 3) {                                                  // vif chunk 3 (zeros)
            int4v zz = {0, 0, 0, 0};
            *(int4v*)(S + VIFA + (3 * 16 + lp) * 16) = zz;
        }

        // ---------- prefetch next group's rows: flies under stages 4-14 ----------
        if (g + 1 < GROUPS) {
            asm volatile("s_waitcnt lgkmcnt(0)" ::: "memory");
            __builtin_amdgcn_sched_barrier(0);
            issue_stage(nb0 + (g + 1) * 64);
            __builtin_amdgcn_sched_barrier(0);
        }

        // ---------- stage 4+5: glob GEMM, two K-passes through 4KB FEATA ----------
        f32x4 ag[4][2] = {};
        #pragma unroll
        for (int pass = 0; pass < 2; ++pass) {
            #pragma unroll
            for (int cc = 0; cc < 4; ++cc) {
                const int base = (pass * 4 + cc) * 4;
                int4v wv4 = { (int)pkf[base], (int)pkf[base + 1],
                              (int)pkf[base + 2], (int)pkf[base + 3] };
                *(int4v*)(S + FEATA + ((q * 4 + cc) * 16 + lp) * 16) = wv4;
            }
            WFENCE();
            #pragma unroll
            for (int s = 0; s < 4; ++s) {
                int4v av = *(int4v*)(S + FEATA + ((s * 4 + q) * 16 + lp) * 16);
                ag[s][0] = MFMA16(SB8(av), SB8(bgf[0][pass]), ag[s][0]);
                ag[s][1] = MFMA16(SB8(av), SB8(bgf[1][pass]), ag[s][1]);
            }
            WFENCE();
        }

        // ---------- stage 6: relu+agg softmax -> im_feat (C-layout lanes) ----------
        f32x4 gg[4][2], wsm[4];
        #pragma unroll
        for (int s = 0; s < 4; ++s) {
            gg[s][0] = relub(ag[s][0], gb0);
            gg[s][1] = relub(ag[s][1], gb1);
            f32x4 zp = gg[s][0] * aw0 + gg[s][1] * aw1;
            zp = bfly16(zp);
            wsm[s] = relub(zp, ab0);
        }
        softmax4(wsm[0], wsm[1], wsm[2], wsm[3]);
        f32x4 im0 = {}, im1 = {};
        #pragma unroll
        for (int s = 0; s < 4; ++s) { im0 += gg[s][0] * wsm[s]; im1 += gg[s][1] * wsm[s]; }

        // ---------- stage 7: scatter im_feat to fc A-fragments (bf16) ----------
        {
            short* fca = (short*)(S + FCA);
            #pragma unroll
            for (int r = 0; r < 4; ++r) {
                fca[((lp >> 3)) * 128     + (q * 4 + r) * 8 + (lp & 7)] = (short)bfbits(im0[r]);
                fca[(2 + (lp >> 3)) * 128 + (q * 4 + r) * 8 + (lp & 7)] = (short)bfbits(im1[r]);
            }
        }
        WFENCE();

        // ---------- stage 8: fc GEMM (rows=pts, cols=16, K=32) ----------
        f32x4 fco;
        {
            int4v av = *(int4v*)(S + FCA + (q * 16 + lp) * 16);
            f32x4 acc = {};
            acc = MFMA16(SB8(av), SB8(bfcf), acc);
            fco = relub(acc, fcb);
        }

        // ---------- stage 9: fc out -> vif chunks 1,2 ----------
        {
            short* vfa = (short*)(S + VIFA);
            #pragma unroll
            for (int r = 0; r < 4; ++r)
                vfa[(1 + (lp >> 3)) * 128 + (q * 4 + r) * 8 + (lp & 7)] = (short)bfbits(fco[r]);
        }
        WFENCE();

        // ---------- stage 10: lr0 GEMM (rows=pts, cols=64, K=32) ----------
        f32x4 x4[4];
        {
            int4v av = *(int4v*)(S + VIFA + (q * 16 + lp) * 16);
            #pragma unroll
            for (int nt = 0; nt < 4; ++nt) {
                f32x4 acc = {};
                acc = MFMA16(SB8(av), SB8(blrf[nt]), acc);
                x4[nt] = relub(acc, lb[nt]);
            }
        }

        // ---------- stage 11: sigma = softplus(sgm_w . x) ----------
        f32x4 sig;
        {
            f32x4 sp = x4[0] * sw[0] + x4[1] * sw[1] + x4[2] * sw[2] + x4[3] * sw[3];
            sp = bfly16(sp);
            #pragma unroll
            for (int i = 0; i < 4; ++i) {
                float z = sp[i] + sb0;
                float e = __expf(-fabsf(z));
                sig[i] = fmaxf(z, 0.f) + __logf(1.f + e);  // log1p(e), e in (0,1]
            }
        }

        // ---------- stage 12: x -> col1 A-fragments (chunks 0..7) ----------
        {
            short* xa = (short*)(S + XA);
            #pragma unroll
            for (int nt = 0; nt < 4; ++nt)
                #pragma unroll
                for (int r = 0; r < 4; ++r)
                    xa[(nt * 2 + (lp >> 3)) * 128 + (q * 4 + r) * 8 + (lp & 7)] =
                        (short)bfbits(x4[nt][r]);
        }
        WFENCE();

        // ---------- stage 13: col1 GEMM, nt-tiled with immediate col2 reduction ----------
        f32x4 zp[4] = {};
        {
            int4v ax0 = *(int4v*)(S + XA + (q * 16 + lp) * 16);
            int4v ax1 = *(int4v*)(S + XA + ((4 + q) * 16 + lp) * 16);
            int4v a2v[4], a3v[4];
            #pragma unroll
            for (int mt = 0; mt < 4; ++mt) {
                const char* a2p = (q < 3) ? (S + VIFA + (q * 16 + lp) * 16)
                                          : (S + RS + (mt * 16 + lp) * 16);
                const char* a3p = (q == 0) ? (S + RS + (64 + mt * 16 + lp) * 16)
                                : (q == 1) ? (S + RS + (128 + mt * 16 + lp) * 16)
                                           : (S + VIFA + (3 * 16 + lp) * 16);  // zeros
                a2v[mt] = *(const int4v*)a2p;
                a3v[mt] = *(const int4v*)a3p;
            }
            #pragma unroll
            for (int nt = 0; nt < 4; ++nt) {
                #pragma unroll
                for (int mt = 0; mt < 4; ++mt) {
                    f32x4 acc = {};
                    acc = MFMA16(SB8(ax0),      SB8(bcf[nt * 4 + 0]), acc);
                    acc = MFMA16(SB8(ax1),      SB8(bcf[nt * 4 + 1]), acc);
                    acc = MFMA16(SB8(a2v[mt]),  SB8(bcf[nt * 4 + 2]), acc);
                    acc = MFMA16(SB8(a3v[mt]),  SB8(bcf[nt * 4 + 3]), acc);
                    f32x4 h = relub(acc, c1b[nt]);
                    zp[mt] += h * c2w[nt];
                }
            }
        }

        // ---------- stage 14: softmax over s, color + store ----------
        f32x4 z2[4];
        #pragma unroll
        for (int s = 0; s < 4; ++s) z2[s] = relub(bfly16(zp[s]), c2b0);
        softmax4(z2[0], z2[1], z2[2], z2[3]);
        if (lp < 4) {
            float cr = 0.f, cg = 0.f, cb = 0.f;
            #pragma unroll
            for (int s = 0; s < 4; ++s) {
                f32x4 rgbv = *(f32x4*)(S + RGB + (s * 16 + q * 4 + lp) * 16);
                float ws = sel4(z2[s], lp);
                cr = fmaf(rgbv[0], ws, cr);
                cg = fmaf(rgbv[1], ws, cg);
                cb = fmaf(rgbv[2], ws, cb);
            }
            f32x4 o = { cr, cg, cb, sel4(sig, lp) };
            *(f32x4*)(out + (size_t)(n0 + q * 4 + lp) * 4) = o;
        }
        WFENCE();
    }
}

extern "C" void kernel_launch(void* const* d_in, const int* in_sizes, int n_in,
                              void* d_out, int out_size, void* d_ws, size_t ws_size,
                              hipStream_t stream) {
    (void)in_sizes; (void)n_in; (void)out_size; (void)ws_size;
    pack_weights<<<dim3(25), dim3(64), 0, stream>>>(
        (const float*)d_in[4],   // glob_w
        (const float*)d_in[8],   // fc_w
        (const float*)d_in[10],  // lr0_w
        (const float*)d_in[14],  // col1_w
        (int4v*)d_ws);
    nerf_mfma<<<dim3(NPTS / (64 * GROUPS)), dim3(256), 0, stream>>>(
        (const float*)d_in[0],  (const float*)d_in[1],
        (const float*)d_in[2],  (const float*)d_in[3],
        (const float*)d_in[5],
        (const float*)d_in[6],  (const float*)d_in[7],
        (const float*)d_in[9],
        (const float*)d_in[11],
        (const float*)d_in[12], (const float*)d_in[13],
        (const float*)d_in[15],
        (const float*)d_in[16], (const float*)d_in[17],
        (const int4v*)d_ws,
        (float*)d_out);
}

// Round 5
// 392.557 us; speedup vs baseline: 1.3289x; 1.1165x over previous
//
#include <hip/hip_runtime.h>
#include <math.h>

#define NPTS   524288
#define GROUPS 4          // 16 pts/wave/group * 4 waves * 4 groups = 256 pts/block

typedef __attribute__((ext_vector_type(8))) short  short8;
typedef __attribute__((ext_vector_type(4))) float  f32x4;
typedef __attribute__((ext_vector_type(4))) int    int4v;

#define MFMA16(a, b, c) __builtin_amdgcn_mfma_f32_16x16x32_bf16((a), (b), (c), 0, 0, 0)
#define SB8(x) __builtin_bit_cast(short8, (x))

// wave-private LDS ordering: compile-time fence only (LDS executes in wave
// program order; block barrier not needed since LDS stripes are per-wave)
#define WFENCE() __builtin_amdgcn_wave_barrier()

// f32 -> bf16 bits, round-half-up
__device__ __forceinline__ unsigned bfbits(float x) {
    union { float f; unsigned u; } a; a.f = x;
    return (a.u + 0x8000u) >> 16;
}
#if __has_builtin(__builtin_amdgcn_cvt_pk_bf16_f32)
__device__ __forceinline__ int pk2(float lo, float hi) {
    return __builtin_bit_cast(int, __builtin_amdgcn_cvt_pk_bf16_f32(lo, hi));
}
#else
__device__ __forceinline__ int pk2(float lo, float hi) {
    union { float f; unsigned u; } a, b; a.f = lo; b.f = hi;
    return (int)(((a.u + 0x8000u) >> 16) | ((b.u + 0x8000u) & 0xFFFF0000u));
}
#endif

__device__ __forceinline__ float frcp(float x) {
#if __has_builtin(__builtin_amdgcn_rcpf)
    return __builtin_amdgcn_rcpf(x);   // ~1 ulp; fine at bf16 tolerance
#else
    return 1.f / x;
#endif
}

// coalesced global -> LDS direct copy, 16B per lane; lds dest must be wave-uniform
__device__ __forceinline__ void gload_lds16(const void* gp, void* lp_) {
    __builtin_amdgcn_global_load_lds(
        (__attribute__((address_space(1))) const void*)gp,
        (__attribute__((address_space(3))) void*)lp_, 16, 0, 0);
}

__device__ __forceinline__ f32x4 relub(f32x4 v, float b) {
    f32x4 r;
    #pragma unroll
    for (int i = 0; i < 4; ++i) r[i] = fmaxf(v[i] + b, 0.f);
    return r;
}

// sum across the 16 lanes of a quad (xor 1,2,4,8), per component
__device__ __forceinline__ f32x4 bfly16(f32x4 v) {
    #pragma unroll
    for (int d = 1; d <= 8; d <<= 1) {
        #pragma unroll
        for (int i = 0; i < 4; ++i) v[i] += __shfl_xor(v[i], d, 64);
    }
    return v;
}

// per-component softmax over 4 vectors (in place -> weights)
__device__ __forceinline__ void softmax4(f32x4& a, f32x4& b, f32x4& c, f32x4& d) {
    #pragma unroll
    for (int i = 0; i < 4; ++i) {
        float m  = fmaxf(fmaxf(a[i], b[i]), fmaxf(c[i], d[i]));
        float e0 = __expf(a[i] - m), e1 = __expf(b[i] - m);
        float e2 = __expf(c[i] - m), e3 = __expf(d[i] - m);
        float inv = frcp(e0 + e1 + e2 + e3);
        a[i] = e0 * inv; b[i] = e1 * inv; c[i] = e2 * inv; d[i] = e3 * inv;
    }
}

// dynamic component extract without scratch (cndmask tree)
__device__ __forceinline__ float sel4(f32x4 v, int r) {
    float a = (r & 1) ? v[1] : v[0];
    float b = (r & 1) ? v[3] : v[2];
    return (r & 2) ? b : a;
}

// ---------------- weight pre-pack kernel: 25 fragments x 64 lanes ----------------
// ws fragment index: bg(nt,ks)=nt*2+ks (0..3), bfc=4, blr(nt)=5+nt, bc(nt,ks)=9+nt*4+ks
// glob K is REORDERED to dword-aligned 20/20/20 sections:
//   k' 0..18 = v(ch), 19 = 0, 20..38 = var(ch), 39 = 0, 40..58 = mean(ch), 59..63 = 0
__global__ __launch_bounds__(64) void pack_weights(
    const float* __restrict__ glob_w, const float* __restrict__ fc_w,
    const float* __restrict__ lr0_w,  const float* __restrict__ col1_w,
    int4v* __restrict__ ws)
{
    const int f = blockIdx.x;
    const int l = threadIdx.x;
    const int q = l >> 4, lp = l & 15;
    short8 r;
    #pragma unroll
    for (int j = 0; j < 8; ++j) {
        int k = q * 8 + j;
        float v = 0.f;
        if (f < 4) {
            int kk = (f & 1) * 32 + k;
            if (kk < 60) {
                int sec = kk / 20, idx = kk - sec * 20;
                if (idx < 19) v = glob_w[((f >> 1) * 16 + lp) * 57 + sec * 19 + idx];
            }
        } else if (f == 4) {
            v = fc_w[lp * 32 + k];
        } else if (f < 9) {
            if (k < 24) v = lr0_w[((f - 5) * 16 + lp) * 24 + k];
        } else {
            int kk = ((f - 9) & 3) * 32 + k;
            if (kk < 111) v = col1_w[(((f - 9) >> 2) * 16 + lp) * 111 + kk];
        }
        r[j] = (short)bfbits(v);
    }
    ws[f * 64 + l] = __builtin_bit_cast(int4v, r);
}

// per-wave LDS region offsets (bytes).
// STG (f32 raw staging, 5888B used) is DISJOINT from the overlay block so
// group g+1's staging can fly while stages 4-14 of group g use FEATA/XA/FCA/VIFA.
#define FEATA 0        // 4s x 4cc x 16row x 16B = 4096 (stages 4-5)
#define XA    0        // 8c x 16row x 16B = 2048       (stages 12-13)
#define FCA   2048     // 4c x 16row x 16B = 1024       (stages 7-8)
#define VIFA  4096     // 4c x 16row x 16B = 1024       (vox / fc out / zeros)
#define RS    6144     // 3c x 64row x 16B = 3072       (raw img rows, bf16)
#define RGB   9216     // 64row x 16B = 1024            (rgb fp32)
#define STG   10240    // 16 pts x 92B = 5888           (live stages 1-3 only)
#define WLDS  16384    // x4 waves = 65536
// block-shared col1 weight cache: 16 frags x 64 lanes x 16B = 16384
// total LDS/block = 81920 -> 2 blocks/CU (gfx950 allows >64KB static LDS)
#define WCOL  (4 * WLDS)

// evaluate one view-head channel + cross-sample mean/var via two INDEPENDENT
// 2-step shuffle chains: var = (Sum v^2 - (Sum v)^2/4)/3  (ddof=1)
#define CHEVAL(c, xv, vv, vrv, mv) do {                                    \
    xv = *(const float*)(st + 4 * (c));                                    \
    float vf_ = fmaf(d0, view_w[4 * (c) + 0], view_b[(c)]);                \
    vf_ = fmaf(d1, view_w[4 * (c) + 1], vf_);                              \
    vf_ = fmaf(d2, view_w[4 * (c) + 2], vf_);                              \
    vf_ = fmaf(d3, view_w[4 * (c) + 3], vf_);                              \
    vv = xv + fmaxf(vf_, 0.f);                                             \
    float p2_ = vv * vv;                                                   \
    float s1_ = vv + __shfl_xor(vv, 16, 64);  s1_ += __shfl_xor(s1_, 32, 64); \
    float s2_ = p2_ + __shfl_xor(p2_, 16, 64); s2_ += __shfl_xor(s2_, 32, 64); \
    mv  = s1_ * 0.25f;                                                     \
    vrv = fmaf(-s1_, mv, s2_) * (1.f / 3.f);                               \
} while (0)

__global__ __launch_bounds__(256, 2) void nerf_mfma(
    const float* __restrict__ vox, const float* __restrict__ img,
    const float* __restrict__ view_w, const float* __restrict__ view_b,
    const float* __restrict__ glob_b,
    const float* __restrict__ aggw_w, const float* __restrict__ aggw_b,
    const float* __restrict__ fc_b,
    const float* __restrict__ lr0_b,
    const float* __restrict__ sgm_w,  const float* __restrict__ sgm_b,
    const float* __restrict__ col1_b,
    const float* __restrict__ col2_w, const float* __restrict__ col2_b,
    const int4v* __restrict__ wsv,
    float* __restrict__ out)
{
    __shared__ int4v smem[(4 * WLDS + 16384) / 16];
    const int tid  = threadIdx.x;
    const int wv   = tid >> 6;
    const int lane = tid & 63;
    const int lp   = lane & 15;   // A-row point / C-column
    const int q    = lane >> 4;   // quad (= sample index in row-stages)
    char* S  = (char*)smem + wv * WLDS;
    char* WC = (char*)smem + WCOL;

    // ---- one-time: cooperative fill of block-shared col1 weight cache ----
    // 16 frags x 64 lanes = 1024 int4v; 256 threads x 4 entries each
    {
        #pragma unroll
        for (int j = 0; j < 4; ++j) {
            int idx = tid * 4 + j;                 // 0..1023
            int f = idx >> 6, l = idx & 63;
            ((int4v*)WC)[idx] = wsv[(9 + f) * 64 + l];
        }
    }
    __syncthreads();

    // ---- per-lane (column-indexed) biases/row-vectors ----
    const float gb0 = glob_b[lp], gb1 = glob_b[16 + lp];
    const float aw0 = aggw_w[lp], aw1 = aggw_w[16 + lp];
    const float fcb = fc_b[lp];
    float lb[4], sw[4], c1b[4], c2w[4];
    #pragma unroll
    for (int nt = 0; nt < 4; ++nt) {
        lb[nt]  = lr0_b[nt * 16 + lp];
        sw[nt]  = sgm_w[nt * 16 + lp];
        c1b[nt] = col1_b[nt * 16 + lp];
        c2w[nt] = col2_w[nt * 16 + lp];
    }
    const float ab0 = aggw_b[0], sb0 = sgm_b[0], c2b0 = col2_b[0];

    // ---- hoisted SMALL weight fragments: 9 x 16B = 36 VGPRs ----
    int4v bgf[2][2], bfcf, blrf[4];
    #pragma unroll
    for (int ks = 0; ks < 2; ++ks) {
        bgf[0][ks] = wsv[(0 + ks) * 64 + lane];
        bgf[1][ks] = wsv[(2 + ks) * 64 + lane];
    }
    bfcf = wsv[4 * 64 + lane];
    #pragma unroll
    for (int nt = 0; nt < 4; ++nt) blrf[nt] = wsv[(5 + nt) * 64 + lane];

    const int nb0 = blockIdx.x * (64 * GROUPS) + wv * 16;

    auto issue_stage = [&](int nbase) {
        const char* gsrc = (const char*)img + (size_t)nbase * 368 + lane * 16;
        #pragma unroll
        for (int r = 0; r < 5; ++r)
            gload_lds16(gsrc + r * 1024, S + STG + r * 1024);
        if (lane < 48)   // last 768B of the 5888B region
            gload_lds16(gsrc + 5 * 1024, S + STG + 5 * 1024);
    };

    // prologue: stage group 0
    issue_stage(nb0);

    #pragma unroll 1
    for (int g = 0; g < GROUPS; ++g) {
        const int n0 = nb0 + g * 64;

        // staging for this group complete (prefetched under previous group's
        // compute; first iter also drains the weight loads once)
        asm volatile("s_waitcnt vmcnt(0)" ::: "memory");
        __builtin_amdgcn_sched_barrier(0);

        // vox loads fly under stage 2/3 (compiler-managed wait at c8 pack)
        const float* vp = vox + (size_t)(n0 + lp) * 8;
        f32x4 v0 = *(const f32x4*)vp;
        f32x4 v1 = *(const f32x4*)(vp + 4);

        // ---------- stage 2+3: view head, mean/var, pack feat (K-reordered) ----------
        const char* st = (const char*)S + STG + (lp * 4 + q) * 92;
        const float d0 = *(const float*)(st + 76);
        const float d1 = *(const float*)(st + 80);
        const float d2 = *(const float*)(st + 84);
        const float d3 = *(const float*)(st + 88);

        unsigned pkf[32];
        pkf[30] = 0u; pkf[31] = 0u;
        unsigned rsbuf[4];
        float x16v = 0.f, x17v = 0.f, x18v = 0.f;

        #pragma unroll
        for (int cp = 0; cp < 10; ++cp) {
            const int a = 2 * cp;
            float xa, va, vra, ma;
            CHEVAL(a, xa, va, vra, ma);
            float xb = 0.f, vb = 0.f, vrb = 0.f, mb = 0.f;
            if (cp < 9) CHEVAL(a + 1, xb, vb, vrb, mb);
            pkf[cp]      = (unsigned)pk2(va,  vb);    // k' = 2cp,2cp+1   (v)
            pkf[10 + cp] = (unsigned)pk2(vra, vrb);   // k' = 20+2cp,...  (var)
            pkf[20 + cp] = (unsigned)pk2(ma,  mb);    // k' = 40+2cp,...  (mean)
            rsbuf[cp & 3] = (cp == 9) ? (unsigned)pk2(xa, d0) : (unsigned)pk2(xa, xb);
            if (cp == 3) {
                int4v w = {(int)rsbuf[0], (int)rsbuf[1], (int)rsbuf[2], (int)rsbuf[3]};
                *(int4v*)(S + RS + (q * 16 + lp) * 16) = w;
            }
            if (cp == 7) {
                int4v w = {(int)rsbuf[0], (int)rsbuf[1], (int)rsbuf[2], (int)rsbuf[3]};
                *(int4v*)(S + RS + 1024 + (q * 16 + lp) * 16) = w;
            }
            if (cp == 8) { x16v = xa; x17v = xb; }
            if (cp == 9) {
                x18v = xa;
                int4v w = {(int)rsbuf[0], (int)rsbuf[1], pk2(d1, d2), pk2(d3, 0.f)};
                *(int4v*)(S + RS + 2048 + (q * 16 + lp) * 16) = w;
            }
        }
        {
            f32x4 rgbv = { x16v, x17v, x18v, 0.f };
            *(f32x4*)(S + RGB + (q * 16 + lp) * 16) = rgbv;
        }
        WFENCE();   // all STG reads consumed; VIFA may be written, STG is dead
        if (q == 0) {                                                  // vif chunk 0 (vox)
            int4v c8 = { pk2(v0[0], v0[1]), pk2(v0[2], v0[3]),
                         pk2(v1[0], v1[1]), pk2(v1[2], v1[3]) };
            *(int4v*)(S + VIFA + lp * 16) = c8;
        }
        if (q == 3) {                                                  // vif chunk 3 (zeros)
            int4v zz = {0, 0, 0, 0};
            *(int4v*)(S + VIFA + (3 * 16 + lp) * 16) = zz;
        }

        // ---------- prefetch next group's rows: flies under stages 4-14 ----------
        if (g + 1 < GROUPS) {
            asm volatile("s_waitcnt lgkmcnt(0)" ::: "memory");
            __builtin_amdgcn_sched_barrier(0);
            issue_stage(nb0 + (g + 1) * 64);
            __builtin_amdgcn_sched_barrier(0);
        }

        // ---------- stage 4+5: glob GEMM, two K-passes through 4KB FEATA ----------
        f32x4 ag[4][2] = {};
        #pragma unroll
        for (int pass = 0; pass < 2; ++pass) {
            #pragma unroll
            for (int cc = 0; cc < 4; ++cc) {
                const int base = (pass * 4 + cc) * 4;
                int4v wv4 = { (int)pkf[base], (int)pkf[base + 1],
                              (int)pkf[base + 2], (int)pkf[base + 3] };
                *(int4v*)(S + FEATA + ((q * 4 + cc) * 16 + lp) * 16) = wv4;
            }
            WFENCE();
            #pragma unroll
            for (int s = 0; s < 4; ++s) {
                int4v av = *(int4v*)(S + FEATA + ((s * 4 + q) * 16 + lp) * 16);
                ag[s][0] = MFMA16(SB8(av), SB8(bgf[0][pass]), ag[s][0]);
                ag[s][1] = MFMA16(SB8(av), SB8(bgf[1][pass]), ag[s][1]);
            }
            WFENCE();
        }

        // ---------- stage 6: relu+agg softmax -> im_feat (C-layout lanes) ----------
        f32x4 gg[4][2], wsm[4];
        #pragma unroll
        for (int s = 0; s < 4; ++s) {
            gg[s][0] = relub(ag[s][0], gb0);
            gg[s][1] = relub(ag[s][1], gb1);
            f32x4 zp = gg[s][0] * aw0 + gg[s][1] * aw1;
            zp = bfly16(zp);
            wsm[s] = relub(zp, ab0);
        }
        softmax4(wsm[0], wsm[1], wsm[2], wsm[3]);
        f32x4 im0 = {}, im1 = {};
        #pragma unroll
        for (int s = 0; s < 4; ++s) { im0 += gg[s][0] * wsm[s]; im1 += gg[s][1] * wsm[s]; }

        // ---------- stage 7: scatter im_feat to fc A-fragments (bf16) ----------
        {
            short* fca = (short*)(S + FCA);
            #pragma unroll
            for (int r = 0; r < 4; ++r) {
                fca[((lp >> 3)) * 128     + (q * 4 + r) * 8 + (lp & 7)] = (short)bfbits(im0[r]);
                fca[(2 + (lp >> 3)) * 128 + (q * 4 + r) * 8 + (lp & 7)] = (short)bfbits(im1[r]);
            }
        }
        WFENCE();

        // ---------- stage 8: fc GEMM (rows=pts, cols=16, K=32) ----------
        f32x4 fco;
        {
            int4v av = *(int4v*)(S + FCA + (q * 16 + lp) * 16);
            f32x4 acc = {};
            acc = MFMA16(SB8(av), SB8(bfcf), acc);
            fco = relub(acc, fcb);
        }

        // ---------- stage 9: fc out -> vif chunks 1,2 ----------
        {
            short* vfa = (short*)(S + VIFA);
            #pragma unroll
            for (int r = 0; r < 4; ++r)
                vfa[(1 + (lp >> 3)) * 128 + (q * 4 + r) * 8 + (lp & 7)] = (short)bfbits(fco[r]);
        }
        WFENCE();

        // ---------- stage 10: lr0 GEMM (rows=pts, cols=64, K=32) ----------
        f32x4 x4[4];
        {
            int4v av = *(int4v*)(S + VIFA + (q * 16 + lp) * 16);
            #pragma unroll
            for (int nt = 0; nt < 4; ++nt) {
                f32x4 acc = {};
                acc = MFMA16(SB8(av), SB8(blrf[nt]), acc);
                x4[nt] = relub(acc, lb[nt]);
            }
        }

        // ---------- stage 11: sigma = softplus(sgm_w . x) ----------
        f32x4 sig;
        {
            f32x4 sp = x4[0] * sw[0] + x4[1] * sw[1] + x4[2] * sw[2] + x4[3] * sw[3];
            sp = bfly16(sp);
            #pragma unroll
            for (int i = 0; i < 4; ++i) {
                float z = sp[i] + sb0;
                float e = __expf(-fabsf(z));
                sig[i] = fmaxf(z, 0.f) + __logf(1.f + e);  // log1p(e), e in (0,1]
            }
        }

        // ---------- stage 12: x -> col1 A-fragments (chunks 0..7) ----------
        {
            short* xa = (short*)(S + XA);
            #pragma unroll
            for (int nt = 0; nt < 4; ++nt)
                #pragma unroll
                for (int r = 0; r < 4; ++r)
                    xa[(nt * 2 + (lp >> 3)) * 128 + (q * 4 + r) * 8 + (lp & 7)] =
                        (short)bfbits(x4[nt][r]);
        }
        WFENCE();

        // ---------- stage 13: col1 GEMM, nt-tiled with immediate col2 reduction ----------
        // B-fragments stream from the block-shared LDS cache (contiguous 1KB
        // per frag -> conflict-free ds_read_b128; latency hides under MFMAs)
        f32x4 zp[4] = {};
        {
            int4v ax0 = *(int4v*)(S + XA + (q * 16 + lp) * 16);
            int4v ax1 = *(int4v*)(S + XA + ((4 + q) * 16 + lp) * 16);
            int4v a2v[4], a3v[4];
            #pragma unroll
            for (int mt = 0; mt < 4; ++mt) {
                const char* a2p = (q < 3) ? (S + VIFA + (q * 16 + lp) * 16)
                                          : (S + RS + (mt * 16 + lp) * 16);
                const char* a3p = (q == 0) ? (S + RS + (64 + mt * 16 + lp) * 16)
                                : (q == 1) ? (S + RS + (128 + mt * 16 + lp) * 16)
                                           : (S + VIFA + (3 * 16 + lp) * 16);  // zeros
                a2v[mt] = *(const int4v*)a2p;
                a3v[mt] = *(const int4v*)a3p;
            }
            #pragma unroll
            for (int nt = 0; nt < 4; ++nt) {
                int4v b0 = *(const int4v*)(WC + (nt * 4 + 0) * 1024 + lane * 16);
                int4v b1 = *(const int4v*)(WC + (nt * 4 + 1) * 1024 + lane * 16);
                int4v b2 = *(const int4v*)(WC + (nt * 4 + 2) * 1024 + lane * 16);
                int4v b3 = *(const int4v*)(WC + (nt * 4 + 3) * 1024 + lane * 16);
                #pragma unroll
                for (int mt = 0; mt < 4; ++mt) {
                    f32x4 acc = {};
                    acc = MFMA16(SB8(ax0),      SB8(b0), acc);
                    acc = MFMA16(SB8(ax1),      SB8(b1), acc);
                    acc = MFMA16(SB8(a2v[mt]),  SB8(b2), acc);
                    acc = MFMA16(SB8(a3v[mt]),  SB8(b3), acc);
                    f32x4 h = relub(acc, c1b[nt]);
                    zp[mt] += h * c2w[nt];
                }
            }
        }

        // ---------- stage 14: softmax over s, color + store ----------
        f32x4 z2[4];
        #pragma unroll
        for (int s = 0; s < 4; ++s) z2[s] = relub(bfly16(zp[s]), c2b0);
        softmax4(z2[0], z2[1], z2[2], z2[3]);
        if (lp < 4) {
            float cr = 0.f, cg = 0.f, cb = 0.f;
            #pragma unroll
            for (int s = 0; s < 4; ++s) {
                f32x4 rgbv = *(f32x4*)(S + RGB + (s * 16 + q * 4 + lp) * 16);
                float ws = sel4(z2[s], lp);
                cr = fmaf(rgbv[0], ws, cr);
                cg = fmaf(rgbv[1], ws, cg);
                cb = fmaf(rgbv[2], ws, cb);
            }
            f32x4 o = { cr, cg, cb, sel4(sig, lp) };
            *(f32x4*)(out + (size_t)(n0 + q * 4 + lp) * 4) = o;
        }
        WFENCE();
    }
}

extern "C" void kernel_launch(void* const* d_in, const int* in_sizes, int n_in,
                              void* d_out, int out_size, void* d_ws, size_t ws_size,
                              hipStream_t stream) {
    (void)in_sizes; (void)n_in; (void)out_size; (void)ws_size;
    pack_weights<<<dim3(25), dim3(64), 0, stream>>>(
        (const float*)d_in[4],   // glob_w
        (const float*)d_in[8],   // fc_w
        (const float*)d_in[10],  // lr0_w
        (const float*)d_in[14],  // col1_w
        (int4v*)d_ws);
    nerf_mfma<<<dim3(NPTS / (64 * GROUPS)), dim3(256), 0, stream>>>(
        (const float*)d_in[0],  (const float*)d_in[1],
        (const float*)d_in[2],  (const float*)d_in[3],
        (const float*)d_in[5],
        (const float*)d_in[6],  (const float*)d_in[7],
        (const float*)d_in[9],
        (const float*)d_in[11],
        (const float*)d_in[12], (const float*)d_in[13],
        (const float*)d_in[15],
        (const float*)d_in[16], (const float*)d_in[17],
        (const int4v*)d_ws,
        (float*)d_out);
}

// Round 7
// 365.673 us; speedup vs baseline: 1.4266x; 1.0735x over previous
//
#include <hip/hip_runtime.h>
#include <math.h>

#define NPTS   524288
#define GROUPS 4          // 16 pts/wave/group * 4 waves * 4 groups = 256 pts/block

typedef __attribute__((ext_vector_type(8))) short  short8;
typedef __attribute__((ext_vector_type(4))) float  f32x4;
typedef __attribute__((ext_vector_type(4))) int    int4v;

#define MFMA16(a, b, c) __builtin_amdgcn_mfma_f32_16x16x32_bf16((a), (b), (c), 0, 0, 0)
#define SB8(x) __builtin_bit_cast(short8, (x))

// wave-private LDS ordering: compile-time fence only (LDS executes in wave
// program order; block barrier not needed since LDS stripes are per-wave)
#define WFENCE() __builtin_amdgcn_wave_barrier()

// f32 -> bf16 bits, round-half-up (scalar path for short scatters)
__device__ __forceinline__ unsigned bfbits(float x) {
    union { float f; unsigned u; } a; a.f = x;
    return (a.u + 0x8000u) >> 16;
}
// f32 pair -> packed bf16x2 via HW converter (1 VALU; no builtin on gfx950)
__device__ __forceinline__ int pk2(float lo, float hi) {
    int r;
    asm("v_cvt_pk_bf16_f32 %0, %1, %2" : "=v"(r) : "v"(lo), "v"(hi));
    return r;
}

__device__ __forceinline__ float frcp(float x) {
#if __has_builtin(__builtin_amdgcn_rcpf)
    return __builtin_amdgcn_rcpf(x);   // ~1 ulp; fine at bf16 tolerance
#else
    return 1.f / x;
#endif
}

// coalesced global -> LDS direct copy, 16B per lane; lds dest must be wave-uniform
__device__ __forceinline__ void gload_lds16(const void* gp, void* lp_) {
    __builtin_amdgcn_global_load_lds(
        (__attribute__((address_space(1))) const void*)gp,
        (__attribute__((address_space(3))) void*)lp_, 16, 0, 0);
}

__device__ __forceinline__ f32x4 relub(f32x4 v, float b) {
    f32x4 r;
    #pragma unroll
    for (int i = 0; i < 4; ++i) r[i] = fmaxf(v[i] + b, 0.f);
    return r;
}

// DPP-based add of a lane-permuted copy (VALU pipe, ~4cy; replaces DS shuffle)
template<int CTRL>
__device__ __forceinline__ f32x4 dpp_add4(f32x4 v) {
    f32x4 r;
    #pragma unroll
    for (int i = 0; i < 4; ++i) {
        int mv = __builtin_amdgcn_update_dpp(
            0, __builtin_bit_cast(int, (float)v[i]), CTRL, 0xF, 0xF, true);
        r[i] = v[i] + __builtin_bit_cast(float, mv);
    }
    return r;
}

// sum across the 16 lanes of a DPP row, per component — rotation-reduce:
// quad_perm xor1, quad_perm xor2 (quad sums), row_ror:4 + row_ror:8 (all quads)
__device__ __forceinline__ f32x4 bfly16(f32x4 v) {
    v = dpp_add4<0xB1>(v);    // quad_perm [1,0,3,2]  (xor 1)
    v = dpp_add4<0x4E>(v);    // quad_perm [2,3,0,1]  (xor 2)
    v = dpp_add4<0x124>(v);   // row_ror:4
    v = dpp_add4<0x128>(v);   // row_ror:8
    return v;
}

// per-component softmax over 4 vectors (in place -> weights)
__device__ __forceinline__ void softmax4(f32x4& a, f32x4& b, f32x4& c, f32x4& d) {
    #pragma unroll
    for (int i = 0; i < 4; ++i) {
        float m  = fmaxf(fmaxf(a[i], b[i]), fmaxf(c[i], d[i]));
        float e0 = __expf(a[i] - m), e1 = __expf(b[i] - m);
        float e2 = __expf(c[i] - m), e3 = __expf(d[i] - m);
        float inv = frcp(e0 + e1 + e2 + e3);
        a[i] = e0 * inv; b[i] = e1 * inv; c[i] = e2 * inv; d[i] = e3 * inv;
    }
}

// dynamic component extract without scratch (cndmask tree)
__device__ __forceinline__ float sel4(f32x4 v, int r) {
    float a = (r & 1) ? v[1] : v[0];
    float b = (r & 1) ? v[3] : v[2];
    return (r & 2) ? b : a;
}

// ---------------- weight pre-pack kernel: 25 fragments x 64 lanes ----------------
// ws fragment index: bg(nt,ks)=nt*2+ks (0..3), bfc=4, blr(nt)=5+nt, bc(nt,ks)=9+nt*4+ks
// glob K is REORDERED to dword-aligned 20/20/20 sections:
//   k' 0..18 = v(ch), 19 = 0, 20..38 = var(ch), 39 = 0, 40..58 = mean(ch), 59..63 = 0
__global__ __launch_bounds__(64) void pack_weights(
    const float* __restrict__ glob_w, const float* __restrict__ fc_w,
    const float* __restrict__ lr0_w,  const float* __restrict__ col1_w,
    int4v* __restrict__ ws)
{
    const int f = blockIdx.x;
    const int l = threadIdx.x;
    const int q = l >> 4, lp = l & 15;
    short8 r;
    #pragma unroll
    for (int j = 0; j < 8; ++j) {
        int k = q * 8 + j;
        float v = 0.f;
        if (f < 4) {
            int kk = (f & 1) * 32 + k;
            if (kk < 60) {
                int sec = kk / 20, idx = kk - sec * 20;
                if (idx < 19) v = glob_w[((f >> 1) * 16 + lp) * 57 + sec * 19 + idx];
            }
        } else if (f == 4) {
            v = fc_w[lp * 32 + k];
        } else if (f < 9) {
            if (k < 24) v = lr0_w[((f - 5) * 16 + lp) * 24 + k];
        } else {
            int kk = ((f - 9) & 3) * 32 + k;
            if (kk < 111) v = col1_w[(((f - 9) >> 2) * 16 + lp) * 111 + kk];
        }
        r[j] = (short)bfbits(v);
    }
    ws[f * 64 + l] = __builtin_bit_cast(int4v, r);
}

// per-wave LDS region offsets (bytes).
// STG (f32 raw staging, 5888B used) is DISJOINT from the overlay block so
// group g+1's staging can fly while stages 4-14 of group g use FEATA/XA/FCA/VIFA.
#define FEATA 0        // 4s x 4cc x 16row x 16B = 4096 (stages 4-5)
#define XA    0        // 8c x 16row x 16B = 2048       (stages 12-13)
#define FCA   2048     // 4c x 16row x 16B = 1024       (stages 7-8)
#define VIFA  4096     // 4c x 16row x 16B = 1024       (vox / fc out / zeros)
#define RS    6144     // 3c x 64row x 16B = 3072       (raw img rows, bf16)
#define RGB   9216     // 64row x 16B = 1024            (rgb fp32)
#define STG   10240    // 16 pts x 92B = 5888           (live stages 1-3 only)
#define WLDS  16384    // x4 waves = 65536
// block-shared col1 weight cache: 16 frags x 64 lanes x 16B = 16384
// total LDS/block = 81920 -> 2 blocks/CU (gfx950 allows >64KB static LDS)
#define WCOL  (4 * WLDS)

// evaluate one view-head channel + cross-sample mean/var via two INDEPENDENT
// 2-step shuffle chains: var = (Sum v^2 - (Sum v)^2/4)/3  (ddof=1)
// (xor16/xor32 cross DPP-row boundaries -> stay as __shfl_xor)
#define CHEVAL(c, xv, vv, vrv, mv) do {                                    \
    xv = *(const float*)(st + 4 * (c));                                    \
    float vf_ = fmaf(d0, view_w[4 * (c) + 0], view_b[(c)]);                \
    vf_ = fmaf(d1, view_w[4 * (c) + 1], vf_);                              \
    vf_ = fmaf(d2, view_w[4 * (c) + 2], vf_);                              \
    vf_ = fmaf(d3, view_w[4 * (c) + 3], vf_);                              \
    vv = xv + fmaxf(vf_, 0.f);                                             \
    float p2_ = vv * vv;                                                   \
    float s1_ = vv + __shfl_xor(vv, 16, 64);  s1_ += __shfl_xor(s1_, 32, 64); \
    float s2_ = p2_ + __shfl_xor(p2_, 16, 64); s2_ += __shfl_xor(s2_, 32, 64); \
    mv  = s1_ * 0.25f;                                                     \
    vrv = fmaf(-s1_, mv, s2_) * (1.f / 3.f);                               \
} while (0)

__global__ __launch_bounds__(256, 2) void nerf_mfma(
    const float* __restrict__ vox, const float* __restrict__ img,
    const float* __restrict__ view_w, const float* __restrict__ view_b,
    const float* __restrict__ glob_b,
    const float* __restrict__ aggw_w, const float* __restrict__ aggw_b,
    const float* __restrict__ fc_b,
    const float* __restrict__ lr0_b,
    const float* __restrict__ sgm_w,  const float* __restrict__ sgm_b,
    const float* __restrict__ col1_b,
    const float* __restrict__ col2_w, const float* __restrict__ col2_b,
    const int4v* __restrict__ wsv,
    float* __restrict__ out)
{
    __shared__ int4v smem[(4 * WLDS + 16384) / 16];
    const int tid  = threadIdx.x;
    const int wv   = tid >> 6;
    const int lane = tid & 63;
    const int lp   = lane & 15;   // A-row point / C-column
    const int q    = lane >> 4;   // quad (= sample index in row-stages)
    char* S  = (char*)smem + wv * WLDS;
    char* WC = (char*)smem + WCOL;

    // ---- one-time: cooperative fill of block-shared col1 weight cache ----
    // 16 frags x 64 lanes = 1024 int4v; 256 threads x 4 entries each
    {
        #pragma unroll
        for (int j = 0; j < 4; ++j) {
            int idx = tid * 4 + j;                 // 0..1023
            int f = idx >> 6, l = idx & 63;
            ((int4v*)WC)[idx] = wsv[(9 + f) * 64 + l];
        }
    }
    __syncthreads();

    // ---- per-lane (column-indexed) biases/row-vectors ----
    const float gb0 = glob_b[lp], gb1 = glob_b[16 + lp];
    const float aw0 = aggw_w[lp], aw1 = aggw_w[16 + lp];
    const float fcb = fc_b[lp];
    float lb[4], sw[4], c1b[4], c2w[4];
    #pragma unroll
    for (int nt = 0; nt < 4; ++nt) {
        lb[nt]  = lr0_b[nt * 16 + lp];
        sw[nt]  = sgm_w[nt * 16 + lp];
        c1b[nt] = col1_b[nt * 16 + lp];
        c2w[nt] = col2_w[nt * 16 + lp];
    }
    const float ab0 = aggw_b[0], sb0 = sgm_b[0], c2b0 = col2_b[0];

    // ---- hoisted SMALL weight fragments: 9 x 16B = 36 VGPRs ----
    int4v bgf[2][2], bfcf, blrf[4];
    #pragma unroll
    for (int ks = 0; ks < 2; ++ks) {
        bgf[0][ks] = wsv[(0 + ks) * 64 + lane];
        bgf[1][ks] = wsv[(2 + ks) * 64 + lane];
    }
    bfcf = wsv[4 * 64 + lane];
    #pragma unroll
    for (int nt = 0; nt < 4; ++nt) blrf[nt] = wsv[(5 + nt) * 64 + lane];

    const int nb0 = blockIdx.x * (64 * GROUPS) + wv * 16;

    auto issue_stage = [&](int nbase) {
        const char* gsrc = (const char*)img + (size_t)nbase * 368 + lane * 16;
        #pragma unroll
        for (int r = 0; r < 5; ++r)
            gload_lds16(gsrc + r * 1024, S + STG + r * 1024);
        if (lane < 48)   // last 768B of the 5888B region
            gload_lds16(gsrc + 5 * 1024, S + STG + 5 * 1024);
    };

    // prologue: stage group 0
    issue_stage(nb0);

    #pragma unroll 1
    for (int g = 0; g < GROUPS; ++g) {
        const int n0 = nb0 + g * 64;

        // staging for this group complete (prefetched under previous group's
        // compute; first iter also drains the weight loads once)
        asm volatile("s_waitcnt vmcnt(0)" ::: "memory");
        __builtin_amdgcn_sched_barrier(0);

        // vox loads fly under stage 2/3 (compiler-managed wait at c8 pack)
        const float* vp = vox + (size_t)(n0 + lp) * 8;
        f32x4 v0 = *(const f32x4*)vp;
        f32x4 v1 = *(const f32x4*)(vp + 4);

        // ---------- stage 2+3: view head, mean/var, pack feat (K-reordered) ----------
        const char* st = (const char*)S + STG + (lp * 4 + q) * 92;
        const float d0 = *(const float*)(st + 76);
        const float d1 = *(const float*)(st + 80);
        const float d2 = *(const float*)(st + 84);
        const float d3 = *(const float*)(st + 88);

        unsigned pkf[32];
        pkf[30] = 0u; pkf[31] = 0u;
        unsigned rsbuf[4];
        float x16v = 0.f, x17v = 0.f, x18v = 0.f;

        #pragma unroll
        for (int cp = 0; cp < 10; ++cp) {
            const int a = 2 * cp;
            float xa, va, vra, ma;
            CHEVAL(a, xa, va, vra, ma);
            float xb = 0.f, vb = 0.f, vrb = 0.f, mb = 0.f;
            if (cp < 9) CHEVAL(a + 1, xb, vb, vrb, mb);
            pkf[cp]      = (unsigned)pk2(va,  vb);    // k' = 2cp,2cp+1   (v)
            pkf[10 + cp] = (unsigned)pk2(vra, vrb);   // k' = 20+2cp,...  (var)
            pkf[20 + cp] = (unsigned)pk2(ma,  mb);    // k' = 40+2cp,...  (mean)
            rsbuf[cp & 3] = (cp == 9) ? (unsigned)pk2(xa, d0) : (unsigned)pk2(xa, xb);
            if (cp == 3) {
                int4v w = {(int)rsbuf[0], (int)rsbuf[1], (int)rsbuf[2], (int)rsbuf[3]};
                *(int4v*)(S + RS + (q * 16 + lp) * 16) = w;
            }
            if (cp == 7) {
                int4v w = {(int)rsbuf[0], (int)rsbuf[1], (int)rsbuf[2], (int)rsbuf[3]};
                *(int4v*)(S + RS + 1024 + (q * 16 + lp) * 16) = w;
            }
            if (cp == 8) { x16v = xa; x17v = xb; }
            if (cp == 9) {
                x18v = xa;
                int4v w = {(int)rsbuf[0], (int)rsbuf[1], pk2(d1, d2), pk2(d3, 0.f)};
                *(int4v*)(S + RS + 2048 + (q * 16 + lp) * 16) = w;
            }
        }
        {
            f32x4 rgbv = { x16v, x17v, x18v, 0.f };
            *(f32x4*)(S + RGB + (q * 16 + lp) * 16) = rgbv;
        }
        WFENCE();   // all STG reads consumed; VIFA may be written, STG is dead
        if (q == 0) {                                                  // vif chunk 0 (vox)
            int4v c8 = { pk2(v0[0], v0[1]), pk2(v0[2], v0[3]),
                         pk2(v1[0], v1[1]), pk2(v1[2], v1[3]) };
            *(int4v*)(S + VIFA + lp * 16) = c8;
        }
        if (q == 3) {                                                  // vif chunk 3 (zeros)
            int4v zz = {0, 0, 0, 0};
            *(int4v*)(S + VIFA + (3 * 16 + lp) * 16) = zz;
        }

        // ---------- prefetch next group's rows: flies under stages 4-14 ----------
        if (g + 1 < GROUPS) {
            asm volatile("s_waitcnt lgkmcnt(0)" ::: "memory");
            __builtin_amdgcn_sched_barrier(0);
            issue_stage(nb0 + (g + 1) * 64);
            __builtin_amdgcn_sched_barrier(0);
        }

        // ---------- stage 4+5: glob GEMM, two K-passes through 4KB FEATA ----------
        f32x4 ag[4][2] = {};
        #pragma unroll
        for (int pass = 0; pass < 2; ++pass) {
            #pragma unroll
            for (int cc = 0; cc < 4; ++cc) {
                const int base = (pass * 4 + cc) * 4;
                int4v wv4 = { (int)pkf[base], (int)pkf[base + 1],
                              (int)pkf[base + 2], (int)pkf[base + 3] };
                *(int4v*)(S + FEATA + ((q * 4 + cc) * 16 + lp) * 16) = wv4;
            }
            WFENCE();
            #pragma unroll
            for (int s = 0; s < 4; ++s) {
                int4v av = *(int4v*)(S + FEATA + ((s * 4 + q) * 16 + lp) * 16);
                ag[s][0] = MFMA16(SB8(av), SB8(bgf[0][pass]), ag[s][0]);
                ag[s][1] = MFMA16(SB8(av), SB8(bgf[1][pass]), ag[s][1]);
            }
            WFENCE();
        }

        // ---------- stage 6: relu+agg softmax -> im_feat (C-layout lanes) ----------
        f32x4 gg[4][2], wsm[4];
        #pragma unroll
        for (int s = 0; s < 4; ++s) {
            gg[s][0] = relub(ag[s][0], gb0);
            gg[s][1] = relub(ag[s][1], gb1);
            f32x4 zp = gg[s][0] * aw0 + gg[s][1] * aw1;
            zp = bfly16(zp);
            wsm[s] = relub(zp, ab0);
        }
        softmax4(wsm[0], wsm[1], wsm[2], wsm[3]);
        f32x4 im0 = {}, im1 = {};
        #pragma unroll
        for (int s = 0; s < 4; ++s) { im0 += gg[s][0] * wsm[s]; im1 += gg[s][1] * wsm[s]; }

        // ---------- stage 7: scatter im_feat to fc A-fragments (bf16) ----------
        {
            short* fca = (short*)(S + FCA);
            #pragma unroll
            for (int r = 0; r < 4; ++r) {
                fca[((lp >> 3)) * 128     + (q * 4 + r) * 8 + (lp & 7)] = (short)bfbits(im0[r]);
                fca[(2 + (lp >> 3)) * 128 + (q * 4 + r) * 8 + (lp & 7)] = (short)bfbits(im1[r]);
            }
        }
        WFENCE();

        // ---------- stage 8: fc GEMM (rows=pts, cols=16, K=32) ----------
        f32x4 fco;
        {
            int4v av = *(int4v*)(S + FCA + (q * 16 + lp) * 16);
            f32x4 acc = {};
            acc = MFMA16(SB8(av), SB8(bfcf), acc);
            fco = relub(acc, fcb);
        }

        // ---------- stage 9: fc out -> vif chunks 1,2 ----------
        {
            short* vfa = (short*)(S + VIFA);
            #pragma unroll
            for (int r = 0; r < 4; ++r)
                vfa[(1 + (lp >> 3)) * 128 + (q * 4 + r) * 8 + (lp & 7)] = (short)bfbits(fco[r]);
        }
        WFENCE();

        // ---------- stage 10: lr0 GEMM (rows=pts, cols=64, K=32) ----------
        f32x4 x4[4];
        {
            int4v av = *(int4v*)(S + VIFA + (q * 16 + lp) * 16);
            #pragma unroll
            for (int nt = 0; nt < 4; ++nt) {
                f32x4 acc = {};
                acc = MFMA16(SB8(av), SB8(blrf[nt]), acc);
                x4[nt] = relub(acc, lb[nt]);
            }
        }

        // ---------- stage 11: sigma = softplus(sgm_w . x) ----------
        f32x4 sig;
        {
            f32x4 sp = x4[0] * sw[0] + x4[1] * sw[1] + x4[2] * sw[2] + x4[3] * sw[3];
            sp = bfly16(sp);
            #pragma unroll
            for (int i = 0; i < 4; ++i) {
                float z = sp[i] + sb0;
                float e = __expf(-fabsf(z));
                sig[i] = fmaxf(z, 0.f) + __logf(1.f + e);  // log1p(e), e in (0,1]
            }
        }

        // ---------- stage 12: x -> col1 A-fragments (chunks 0..7) ----------
        {
            short* xa = (short*)(S + XA);
            #pragma unroll
            for (int nt = 0; nt < 4; ++nt)
                #pragma unroll
                for (int r = 0; r < 4; ++r)
                    xa[(nt * 2 + (lp >> 3)) * 128 + (q * 4 + r) * 8 + (lp & 7)] =
                        (short)bfbits(x4[nt][r]);
        }
        WFENCE();

        // ---------- stage 13: col1 GEMM, nt-tiled with immediate col2 reduction ----------
        // B-fragments stream from the block-shared LDS cache (contiguous 1KB
        // per frag -> conflict-free ds_read_b128; latency hides under MFMAs)
        f32x4 zp[4] = {};
        {
            int4v ax0 = *(int4v*)(S + XA + (q * 16 + lp) * 16);
            int4v ax1 = *(int4v*)(S + XA + ((4 + q) * 16 + lp) * 16);
            int4v a2v[4], a3v[4];
            #pragma unroll
            for (int mt = 0; mt < 4; ++mt) {
                const char* a2p = (q < 3) ? (S + VIFA + (q * 16 + lp) * 16)
                                          : (S + RS + (mt * 16 + lp) * 16);
                const char* a3p = (q == 0) ? (S + RS + (64 + mt * 16 + lp) * 16)
                                : (q == 1) ? (S + RS + (128 + mt * 16 + lp) * 16)
                                           : (S + VIFA + (3 * 16 + lp) * 16);  // zeros
                a2v[mt] = *(const int4v*)a2p;
                a3v[mt] = *(const int4v*)a3p;
            }
            #pragma unroll
            for (int nt = 0; nt < 4; ++nt) {
                int4v b0 = *(const int4v*)(WC + (nt * 4 + 0) * 1024 + lane * 16);
                int4v b1 = *(const int4v*)(WC + (nt * 4 + 1) * 1024 + lane * 16);
                int4v b2 = *(const int4v*)(WC + (nt * 4 + 2) * 1024 + lane * 16);
                int4v b3 = *(const int4v*)(WC + (nt * 4 + 3) * 1024 + lane * 16);
                #pragma unroll
                for (int mt = 0; mt < 4; ++mt) {
                    f32x4 acc = {};
                    acc = MFMA16(SB8(ax0),      SB8(b0), acc);
                    acc = MFMA16(SB8(ax1),      SB8(b1), acc);
                    acc = MFMA16(SB8(a2v[mt]),  SB8(b2), acc);
                    acc = MFMA16(SB8(a3v[mt]),  SB8(b3), acc);
                    f32x4 h = relub(acc, c1b[nt]);
                    zp[mt] += h * c2w[nt];
                }
            }
        }

        // ---------- stage 14: softmax over s, color + store ----------
        f32x4 z2[4];
        #pragma unroll
        for (int s = 0; s < 4; ++s) z2[s] = relub(bfly16(zp[s]), c2b0);
        softmax4(z2[0], z2[1], z2[2], z2[3]);
        if (lp < 4) {
            float cr = 0.f, cg = 0.f, cb = 0.f;
            #pragma unroll
            for (int s = 0; s < 4; ++s) {
                f32x4 rgbv = *(f32x4*)(S + RGB + (s * 16 + q * 4 + lp) * 16);
                float ws = sel4(z2[s], lp);
                cr = fmaf(rgbv[0], ws, cr);
                cg = fmaf(rgbv[1], ws, cg);
                cb = fmaf(rgbv[2], ws, cb);
            }
            f32x4 o = { cr, cg, cb, sel4(sig, lp) };
            *(f32x4*)(out + (size_t)(n0 + q * 4 + lp) * 4) = o;
        }
        WFENCE();
    }
}

extern "C" void kernel_launch(void* const* d_in, const int* in_sizes, int n_in,
                              void* d_out, int out_size, void* d_ws, size_t ws_size,
                              hipStream_t stream) {
    (void)in_sizes; (void)n_in; (void)out_size; (void)ws_size;
    pack_weights<<<dim3(25), dim3(64), 0, stream>>>(
        (const float*)d_in[4],   // glob_w
        (const float*)d_in[8],   // fc_w
        (const float*)d_in[10],  // lr0_w
        (const float*)d_in[14],  // col1_w
        (int4v*)d_ws);
    nerf_mfma<<<dim3(NPTS / (64 * GROUPS)), dim3(256), 0, stream>>>(
        (const float*)d_in[0],  (const float*)d_in[1],
        (const float*)d_in[2],  (const float*)d_in[3],
        (const float*)d_in[5],
        (const float*)d_in[6],  (const float*)d_in[7],
        (const float*)d_in[9],
        (const float*)d_in[11],
        (const float*)d_in[12], (const float*)d_in[13],
        (const float*)d_in[15],
        (const float*)d_in[16], (const float*)d_in[17],
        (const int4v*)d_ws,
        (float*)d_out);
}